// Round 4
// baseline (1231.711 us; speedup 1.0000x reference)
//
#include <hip/hip_runtime.h>
#include <math.h>

#define HEADS 4
#define HD 32
#define DIM 128
#define NEG_SLOPE 0.2f
#define EPS_SM 1e-8f
#define EPS_LN 1e-5f
#define GROWS 64

__device__ __forceinline__ float lrelu(float x) { return x > 0.f ? x : NEG_SLOPE * x; }
__device__ __forceinline__ unsigned bf16rne(float x) {
    unsigned b = __float_as_uint(x);
    return (b + 0x7fffu + ((b >> 16) & 1u)) >> 16;
}

// ---------------- fused dual GEMM: h@W -> outP, h@W_self -> outS ----------------
__global__ __launch_bounds__(256) void dual_gemm_k(const float* __restrict__ h,
                                                   const float* __restrict__ W,
                                                   const float* __restrict__ V,
                                                   float* __restrict__ outP,
                                                   float* __restrict__ outS, int N) {
    __shared__ float As[32][GROWS];   // k-major A chunk
    __shared__ float Ws[32][DIM];
    __shared__ float Vs[32][DIM];
    const int tid = threadIdx.x;
    const int cg = tid & 15;
    const int rg = tid >> 4;
    const int row0 = blockIdx.x * GROWS;

    float accP[4][8], accS[4][8];
#pragma unroll
    for (int r = 0; r < 4; ++r)
#pragma unroll
        for (int c = 0; c < 8; ++c) { accP[r][c] = 0.f; accS[r][c] = 0.f; }

    for (int kc = 0; kc < 4; ++kc) {
        __syncthreads();
#pragma unroll
        for (int p = 0; p < 2; ++p) {
            int f = tid + p * 256;
            int r = f >> 3, c4 = f & 7;
            float4 v = make_float4(0.f, 0.f, 0.f, 0.f);
            if (row0 + r < N) v = ((const float4*)h)[(size_t)(row0 + r) * 32 + kc * 8 + c4];
            As[c4 * 4 + 0][r] = v.x;
            As[c4 * 4 + 1][r] = v.y;
            As[c4 * 4 + 2][r] = v.z;
            As[c4 * 4 + 3][r] = v.w;
        }
#pragma unroll
        for (int p = 0; p < 4; ++p) {
            int f = tid + p * 256;
            int lk = f >> 5, c4 = f & 31;
            ((float4*)&Ws[lk][0])[c4] = ((const float4*)W)[(size_t)(kc * 32 + lk) * 32 + c4];
            ((float4*)&Vs[lk][0])[c4] = ((const float4*)V)[(size_t)(kc * 32 + lk) * 32 + c4];
        }
        __syncthreads();
#pragma unroll
        for (int kk = 0; kk < 32; ++kk) {
            float4 a = *(const float4*)&As[kk][rg * 4];
            float4 w0 = *(const float4*)&Ws[kk][cg * 8];
            float4 w1 = *(const float4*)&Ws[kk][cg * 8 + 4];
            float4 v0 = *(const float4*)&Vs[kk][cg * 8];
            float4 v1 = *(const float4*)&Vs[kk][cg * 8 + 4];
            float av[4] = {a.x, a.y, a.z, a.w};
            float wv[8] = {w0.x, w0.y, w0.z, w0.w, w1.x, w1.y, w1.z, w1.w};
            float vv[8] = {v0.x, v0.y, v0.z, v0.w, v1.x, v1.y, v1.z, v1.w};
#pragma unroll
            for (int r = 0; r < 4; ++r)
#pragma unroll
                for (int c = 0; c < 8; ++c) {
                    accP[r][c] += av[r] * wv[c];
                    accS[r][c] += av[r] * vv[c];
                }
        }
    }
#pragma unroll
    for (int r = 0; r < 4; ++r) {
        int row = row0 + rg * 4 + r;
        if (row < N) {
            float4 p0 = make_float4(accP[r][0], accP[r][1], accP[r][2], accP[r][3]);
            float4 p1 = make_float4(accP[r][4], accP[r][5], accP[r][6], accP[r][7]);
            float4 s0 = make_float4(accS[r][0], accS[r][1], accS[r][2], accS[r][3]);
            float4 s1 = make_float4(accS[r][4], accS[r][5], accS[r][6], accS[r][7]);
            ((float4*)outP)[(size_t)row * 32 + cg * 2] = p0;
            ((float4*)outP)[(size_t)row * 32 + cg * 2 + 1] = p1;
            ((float4*)outS)[(size_t)row * 32 + cg * 2] = s0;
            ((float4*)outS)[(size_t)row * 32 + cg * 2 + 1] = s1;
        }
    }
}

// ------------- pack h_proj channels (c, c+64) into one bf16x2 dword -------------
__global__ __launch_bounds__(256) void pack_k(const float* __restrict__ hp,
                                              unsigned* __restrict__ hp_pk, int N) {
    int idx = blockIdx.x * 256 + threadIdx.x;
    if (idx >= N * 64) return;
    int n = idx >> 6, c = idx & 63;
    float x0 = hp[(size_t)n * DIM + c];
    float x1 = hp[(size_t)n * DIM + c + 64];
    hp_pk[idx] = bf16rne(x0) | (bf16rne(x1) << 16);
}

// ------------- per-node per-head attention scalars (4 tables, N*4) -------------
__global__ __launch_bounds__(256) void node_dots_k(const float* __restrict__ hp,
                                                   const float* __restrict__ a_in,
                                                   const float* __restrict__ a_out,
                                                   float* __restrict__ pA0, float* __restrict__ pA1,
                                                   float* __restrict__ pB0, float* __restrict__ pB1,
                                                   int N) {
    int idx = blockIdx.x * 256 + threadIdx.x;
    if (idx >= N * HEADS) return;
    int n = idx >> 2, hh = idx & 3;
    const float4* v4 = (const float4*)(hp + (size_t)n * DIM + hh * HD);
    const float4* ai = (const float4*)(a_in + hh * 2 * HD);
    const float4* ao = (const float4*)(a_out + hh * 2 * HD);
    float s0 = 0.f, s1 = 0.f, s2 = 0.f, s3 = 0.f;
#pragma unroll
    for (int i = 0; i < 8; ++i) {
        float4 v = v4[i];
        float4 x0 = ai[i], x1 = ai[8 + i], y0 = ao[i], y1 = ao[8 + i];
        s0 += v.x * x0.x + v.y * x0.y + v.z * x0.z + v.w * x0.w;
        s1 += v.x * x1.x + v.y * x1.y + v.z * x1.z + v.w * x1.w;
        s2 += v.x * y0.x + v.y * y0.y + v.z * y0.z + v.w * y0.w;
        s3 += v.x * y1.x + v.y * y1.y + v.z * y1.z + v.w * y1.w;
    }
    pA0[idx] = s0; pA1[idx] = s1; pB0[idx] = s2; pB1[idx] = s3;
}

// ---------------- bucketed CSR build ----------------
// Buckets of 256 segments. Segment = receiver d (in-dir) or N+s (out-dir).

__global__ __launch_bounds__(256) void bcnt_k(const int* __restrict__ ei, int* __restrict__ bcnt,
                                              int E, int N, int NB) {
    __shared__ int lh[1024];
    const int tid = threadIdx.x;
    if (NB <= 1024) {
        for (int i = tid; i < 1024; i += 256) lh[i] = 0;
        __syncthreads();
        for (int e = blockIdx.x * 256 + tid; e < E; e += gridDim.x * 256) {
            int s = ei[e], d = ei[E + e];
            atomicAdd(&lh[d >> 8], 1);
            atomicAdd(&lh[(N + s) >> 8], 1);
        }
        __syncthreads();
        for (int i = tid; i < NB; i += 256) {
            int v = lh[i];
            if (v) atomicAdd(&bcnt[i], v);
        }
    } else {
        for (int e = blockIdx.x * 256 + tid; e < E; e += gridDim.x * 256) {
            int s = ei[e], d = ei[E + e];
            atomicAdd(&bcnt[d >> 8], 1);
            atomicAdd(&bcnt[(N + s) >> 8], 1);
        }
    }
}

__global__ __launch_bounds__(256) void bscan_k(const int* __restrict__ bcnt,
                                               int* __restrict__ bbase, int* __restrict__ bcur,
                                               int NB) {
    __shared__ int ls[256];
    int t = threadIdx.x;
    int per = (NB + 255) / 256;
    int b0 = t * per, b1 = min(b0 + per, NB);
    int sum = 0;
    for (int j = b0; j < b1; ++j) sum += bcnt[j];
    ls[t] = sum;
    __syncthreads();
#pragma unroll
    for (int d = 1; d < 256; d <<= 1) {
        int u = (t >= d) ? ls[t - d] : 0;
        __syncthreads();
        ls[t] += u;
        __syncthreads();
    }
    int base = (t == 0) ? 0 : ls[t - 1];
    for (int j = b0; j < b1; ++j) { bbase[j] = base; bcur[j] = base; base += bcnt[j]; }
}

// partition: rec[p] = sender | (seg_local << 20); positions sequential per bucket
__global__ __launch_bounds__(256) void part_k(const int* __restrict__ ei, int* __restrict__ bcur,
                                              unsigned* __restrict__ rec, int E, int N) {
    int e = blockIdx.x * 256 + threadIdx.x;
    if (e >= E) return;
    int s = ei[e], d = ei[E + e];
    int p = atomicAdd(&bcur[d >> 8], 1);
    rec[p] = (unsigned)s | ((unsigned)(d & 255) << 20);
    int so = N + s;
    int q = atomicAdd(&bcur[so >> 8], 1);
    rec[q] = (unsigned)d | ((unsigned)(so & 255) << 20);
}

// per-bucket: LDS per-segment count -> scan -> write off[] and csr[]
__global__ __launch_bounds__(256) void build_k(const unsigned* __restrict__ rec,
                                               const int* __restrict__ bbase,
                                               int* __restrict__ off, int* __restrict__ csr,
                                               int M, int twoE, int NB) {
    __shared__ int lcnt[256];
    __shared__ int lcur[256];
    __shared__ int ltmp[256];
    const int b = blockIdx.x;
    const int t = threadIdx.x;
    const int base = bbase[b];
    const int cnt = ((b == NB - 1) ? twoE : bbase[b + 1]) - base;
    const int seg0 = b << 8;
    lcnt[t] = 0;
    __syncthreads();
    for (int k = t; k < cnt; k += 256) atomicAdd(&lcnt[rec[base + k] >> 20], 1);
    __syncthreads();
    int v = lcnt[t];
    ltmp[t] = v;
    __syncthreads();
#pragma unroll
    for (int d = 1; d < 256; d <<= 1) {
        int u = (t >= d) ? ltmp[t - d] : 0;
        __syncthreads();
        ltmp[t] += u;
        __syncthreads();
    }
    int excl = ltmp[t] - v;
    lcur[t] = excl;
    if (seg0 + t < M) off[seg0 + t] = base + excl;
    if (b == NB - 1 && t == 0) off[M] = twoE;
    __syncthreads();
    for (int k = t; k < cnt; k += 256) {
        unsigned r = rec[base + k];
        int pos = atomicAdd(&lcur[r >> 20], 1);
        csr[base + pos] = (int)(r & 0xFFFFFu);
    }
}

// ---------------- fused: per-node softmax-aggregate (both dirs) + combine + LN ----------------
__global__ __launch_bounds__(256) void node_aggr_ln_k(const unsigned* __restrict__ hp_pk,
                                                      const float* __restrict__ h_self,
                                                      const float* __restrict__ pA0, const float* __restrict__ pA1,
                                                      const float* __restrict__ pB0, const float* __restrict__ pB1,
                                                      const int* __restrict__ off, const int* __restrict__ csr,
                                                      const float* __restrict__ bias,
                                                      const float* __restrict__ gamma,
                                                      const float* __restrict__ beta,
                                                      float* __restrict__ out, int N) {
    int wave = threadIdx.x >> 6;
    int lane = threadIdx.x & 63;
    int n = blockIdx.x * 4 + wave;
    if (n >= N) return;
    const int hsel = lane >> 5;

    float acc0 = 0.f, acc1 = 0.f;

#pragma unroll
    for (int dir = 0; dir < 2; ++dir) {
        const int seg = (dir == 0) ? n : N + n;
        const int beg = off[seg], end = off[seg + 1];
        const int len = end - beg;
        if (len == 0) continue;
        const float* __restrict__ p0 = (dir == 0) ? pA0 : pB0;
        const float* __restrict__ p1 = (dir == 0) ? pA1 : pB1;
        float4 r1 = ((const float4*)p1)[n];

        if (len <= 64) {
            int sid = 0;
            float e0 = -INFINITY, e1 = -INFINITY, e2 = -INFINITY, e3 = -INFINITY;
            if (lane < len) {
                sid = csr[beg + lane];
                float4 r0 = ((const float4*)p0)[sid];
                e0 = lrelu(r0.x + r1.x);
                e1 = lrelu(r0.y + r1.y);
                e2 = lrelu(r0.z + r1.z);
                e3 = lrelu(r0.w + r1.w);
            }
            float m0 = e0, m1 = e1, m2 = e2, m3 = e3;
#pragma unroll
            for (int d = 1; d < 64; d <<= 1) {
                m0 = fmaxf(m0, __shfl_xor(m0, d, 64));
                m1 = fmaxf(m1, __shfl_xor(m1, d, 64));
                m2 = fmaxf(m2, __shfl_xor(m2, d, 64));
                m3 = fmaxf(m3, __shfl_xor(m3, d, 64));
            }
            float w0 = 0.f, w1 = 0.f, w2 = 0.f, w3 = 0.f;
            if (lane < len) {
                w0 = expf(e0 - m0); w1 = expf(e1 - m1);
                w2 = expf(e2 - m2); w3 = expf(e3 - m3);
            }
            float s0 = w0, s1 = w1, s2 = w2, s3 = w3;
#pragma unroll
            for (int d = 1; d < 64; d <<= 1) {
                s0 += __shfl_xor(s0, d, 64);
                s1 += __shfl_xor(s1, d, 64);
                s2 += __shfl_xor(s2, d, 64);
                s3 += __shfl_xor(s3, d, 64);
            }
            w0 *= 1.f / (s0 + EPS_SM);
            w1 *= 1.f / (s1 + EPS_SM);
            w2 *= 1.f / (s2 + EPS_SM);
            w3 *= 1.f / (s3 + EPS_SM);

            if (len <= 32) {
                float t1 = __shfl_xor(w1, 32, 64);
                float t3 = __shfl_xor(w3, 32, 64);
                float uA = hsel ? t1 : w0;
                float uB = hsel ? t3 : w2;
                int src = (hsel << 5);
                for (int j = 0; j < len; ++j) {
                    int sj = __shfl(sid, j, 64);
                    float wa = __shfl(uA, j + src, 64);
                    float wb = __shfl(uB, j + src, 64);
                    unsigned pk = hp_pk[(size_t)sj * 64 + lane];
                    acc0 += wa * __uint_as_float(pk << 16);
                    acc1 += wb * __uint_as_float(pk & 0xffff0000u);
                }
            } else {
                for (int j = 0; j < len; ++j) {
                    int sj = __shfl(sid, j, 64);
                    float w0j = __shfl(w0, j, 64);
                    float w1j = __shfl(w1, j, 64);
                    float w2j = __shfl(w2, j, 64);
                    float w3j = __shfl(w3, j, 64);
                    float wa = hsel ? w1j : w0j;
                    float wb = hsel ? w3j : w2j;
                    unsigned pk = hp_pk[(size_t)sj * 64 + lane];
                    acc0 += wa * __uint_as_float(pk << 16);
                    acc1 += wb * __uint_as_float(pk & 0xffff0000u);
                }
            }
        } else {
            float m0 = -INFINITY, m1 = -INFINITY, m2 = -INFINITY, m3 = -INFINITY;
            for (int base = beg; base < end; base += 64) {
                int j = base + lane;
                if (j < end) {
                    int sid = csr[j];
                    float4 r0 = ((const float4*)p0)[sid];
                    m0 = fmaxf(m0, lrelu(r0.x + r1.x));
                    m1 = fmaxf(m1, lrelu(r0.y + r1.y));
                    m2 = fmaxf(m2, lrelu(r0.z + r1.z));
                    m3 = fmaxf(m3, lrelu(r0.w + r1.w));
                }
            }
#pragma unroll
            for (int d = 1; d < 64; d <<= 1) {
                m0 = fmaxf(m0, __shfl_xor(m0, d, 64));
                m1 = fmaxf(m1, __shfl_xor(m1, d, 64));
                m2 = fmaxf(m2, __shfl_xor(m2, d, 64));
                m3 = fmaxf(m3, __shfl_xor(m3, d, 64));
            }
            float s0 = 0.f, s1 = 0.f, s2 = 0.f, s3 = 0.f;
            for (int base = beg; base < end; base += 64) {
                int j = base + lane;
                if (j < end) {
                    int sid = csr[j];
                    float4 r0 = ((const float4*)p0)[sid];
                    s0 += expf(lrelu(r0.x + r1.x) - m0);
                    s1 += expf(lrelu(r0.y + r1.y) - m1);
                    s2 += expf(lrelu(r0.z + r1.z) - m2);
                    s3 += expf(lrelu(r0.w + r1.w) - m3);
                }
            }
#pragma unroll
            for (int d = 1; d < 64; d <<= 1) {
                s0 += __shfl_xor(s0, d, 64);
                s1 += __shfl_xor(s1, d, 64);
                s2 += __shfl_xor(s2, d, 64);
                s3 += __shfl_xor(s3, d, 64);
            }
            const float is0 = 1.f / (s0 + EPS_SM);
            const float is1 = 1.f / (s1 + EPS_SM);
            const float is2 = 1.f / (s2 + EPS_SM);
            const float is3 = 1.f / (s3 + EPS_SM);
            for (int base = beg; base < end; base += 64) {
                int cnt = min(64, end - base);
                int sid = 0;
                float w0 = 0.f, w1 = 0.f, w2 = 0.f, w3 = 0.f;
                if (lane < cnt) {
                    sid = csr[base + lane];
                    float4 r0 = ((const float4*)p0)[sid];
                    w0 = expf(lrelu(r0.x + r1.x) - m0) * is0;
                    w1 = expf(lrelu(r0.y + r1.y) - m1) * is1;
                    w2 = expf(lrelu(r0.z + r1.z) - m2) * is2;
                    w3 = expf(lrelu(r0.w + r1.w) - m3) * is3;
                }
                for (int j = 0; j < cnt; ++j) {
                    int sj = __shfl(sid, j, 64);
                    float w0j = __shfl(w0, j, 64);
                    float w1j = __shfl(w1, j, 64);
                    float w2j = __shfl(w2, j, 64);
                    float w3j = __shfl(w3, j, 64);
                    float wa = hsel ? w1j : w0j;
                    float wb = hsel ? w3j : w2j;
                    unsigned pk = hp_pk[(size_t)sj * 64 + lane];
                    acc0 += wa * __uint_as_float(pk << 16);
                    acc1 += wb * __uint_as_float(pk & 0xffff0000u);
                }
            }
        }
    }

    size_t bb = (size_t)n * DIM;
    float x0 = h_self[bb + lane] + acc0 + bias[lane];
    float x1 = h_self[bb + lane + 64] + acc1 + bias[lane + 64];
    float sum = x0 + x1, sq = x0 * x0 + x1 * x1;
#pragma unroll
    for (int m = 1; m < 64; m <<= 1) {
        sum += __shfl_xor(sum, m, 64);
        sq += __shfl_xor(sq, m, 64);
    }
    float mean = sum * (1.f / 128.f);
    float var = sq * (1.f / 128.f) - mean * mean;
    float inv = rsqrtf(var + EPS_LN);
    out[bb + lane] = (x0 - mean) * inv * gamma[lane] + beta[lane];
    out[bb + lane + 64] = (x1 - mean) * inv * gamma[lane + 64] + beta[lane + 64];
}

extern "C" void kernel_launch(void* const* d_in, const int* in_sizes, int n_in,
                              void* d_out, int out_size, void* d_ws, size_t ws_size,
                              hipStream_t stream) {
    const float* h      = (const float*)d_in[0];
    const int*   ei     = (const int*)d_in[1];
    const float* W      = (const float*)d_in[2];
    const float* W_self = (const float*)d_in[3];
    const float* a_in   = (const float*)d_in[4];
    const float* a_out  = (const float*)d_in[5];
    const float* bias   = (const float*)d_in[6];
    const float* gamma  = (const float*)d_in[7];
    const float* beta   = (const float*)d_in[8];
    float* out = (float*)d_out;

    const int N = in_sizes[0] / DIM;
    const int E = in_sizes[1] / 2;
    const int M = 2 * N;
    const int NB = (M + 255) / 256;
    const int twoE = 2 * E;

    // workspace layout
    float* ws = (float*)d_ws;
    size_t off_f = 0;
    float* h_proj = ws + off_f; off_f += (size_t)N * DIM;
    float* h_self = ws + off_f; off_f += (size_t)N * DIM;
    unsigned* hp_pk = (unsigned*)(ws + off_f); off_f += (size_t)N * 64;
    float* pA0 = ws + off_f; off_f += (size_t)N * 4;
    float* pA1 = ws + off_f; off_f += (size_t)N * 4;
    float* pB0 = ws + off_f; off_f += (size_t)N * 4;
    float* pB1 = ws + off_f; off_f += (size_t)N * 4;
    int* ip = (int*)(ws + off_f);
    size_t off_i = 0;
    int* bcnt  = ip + off_i; off_i += NB;
    int* bbase = ip + off_i; off_i += (size_t)NB + 1;
    int* bcur  = ip + off_i; off_i += NB;
    int* off   = ip + off_i; off_i += (size_t)M + 1;
    unsigned* rec = (unsigned*)(ip + off_i); off_i += (size_t)twoE;
    int* csr   = ip + off_i; off_i += (size_t)twoE;

    // ---- bucketed CSR build ----
    hipMemsetAsync(bcnt, 0, (size_t)NB * sizeof(int), stream);
    bcnt_k<<<512, 256, 0, stream>>>(ei, bcnt, E, N, NB);
    bscan_k<<<1, 256, 0, stream>>>(bcnt, bbase, bcur, NB);
    part_k<<<(E + 255) / 256, 256, 0, stream>>>(ei, bcur, rec, E, N);
    build_k<<<NB, 256, 0, stream>>>(rec, bbase, off, csr, M, twoE, NB);

    // ---- projections ----
    dual_gemm_k<<<(N + GROWS - 1) / GROWS, 256, 0, stream>>>(h, W, W_self, h_proj, h_self, N);
    node_dots_k<<<(N * 4 + 255) / 256, 256, 0, stream>>>(h_proj, a_in, a_out, pA0, pA1, pB0, pB1, N);
    pack_k<<<(N * 64 + 255) / 256, 256, 0, stream>>>(h_proj, hp_pk, N);

    // ---- fused aggregate + LN ----
    node_aggr_ln_k<<<(N + 3) / 4, 256, 0, stream>>>(hp_pk, h_self, pA0, pA1, pB0, pB1,
                                                    off, csr, bias, gamma, beta, out, N);
}

// Round 5
// 956.801 us; speedup vs baseline: 1.2873x; 1.2873x over previous
//
#include <hip/hip_runtime.h>
#include <math.h>

#define HEADS 4
#define HD 32
#define DIM 128
#define NEG_SLOPE 0.2f
#define EPS_SM 1e-8f
#define EPS_LN 1e-5f
#define GROWS 64
#define SEGS_PER_BKT 8   // 8 segments per bucket -> ~25K cursors, short atomic chains

__device__ __forceinline__ float lrelu(float x) { return x > 0.f ? x : NEG_SLOPE * x; }
__device__ __forceinline__ unsigned bf16rne(float x) {
    unsigned b = __float_as_uint(x);
    return (b + 0x7fffu + ((b >> 16) & 1u)) >> 16;
}

// ---------------- fused dual GEMM: h@W -> outP, h@W_self -> outS ----------------
__global__ __launch_bounds__(256) void dual_gemm_k(const float* __restrict__ h,
                                                   const float* __restrict__ W,
                                                   const float* __restrict__ V,
                                                   float* __restrict__ outP,
                                                   float* __restrict__ outS, int N) {
    __shared__ float As[32][GROWS];
    __shared__ float Ws[32][DIM];
    __shared__ float Vs[32][DIM];
    const int tid = threadIdx.x;
    const int cg = tid & 15;
    const int rg = tid >> 4;
    const int row0 = blockIdx.x * GROWS;

    float accP[4][8], accS[4][8];
#pragma unroll
    for (int r = 0; r < 4; ++r)
#pragma unroll
        for (int c = 0; c < 8; ++c) { accP[r][c] = 0.f; accS[r][c] = 0.f; }

    for (int kc = 0; kc < 4; ++kc) {
        __syncthreads();
#pragma unroll
        for (int p = 0; p < 2; ++p) {
            int f = tid + p * 256;
            int r = f >> 3, c4 = f & 7;
            float4 v = make_float4(0.f, 0.f, 0.f, 0.f);
            if (row0 + r < N) v = ((const float4*)h)[(size_t)(row0 + r) * 32 + kc * 8 + c4];
            As[c4 * 4 + 0][r] = v.x;
            As[c4 * 4 + 1][r] = v.y;
            As[c4 * 4 + 2][r] = v.z;
            As[c4 * 4 + 3][r] = v.w;
        }
#pragma unroll
        for (int p = 0; p < 4; ++p) {
            int f = tid + p * 256;
            int lk = f >> 5, c4 = f & 31;
            ((float4*)&Ws[lk][0])[c4] = ((const float4*)W)[(size_t)(kc * 32 + lk) * 32 + c4];
            ((float4*)&Vs[lk][0])[c4] = ((const float4*)V)[(size_t)(kc * 32 + lk) * 32 + c4];
        }
        __syncthreads();
#pragma unroll
        for (int kk = 0; kk < 32; ++kk) {
            float4 a = *(const float4*)&As[kk][rg * 4];
            float4 w0 = *(const float4*)&Ws[kk][cg * 8];
            float4 w1 = *(const float4*)&Ws[kk][cg * 8 + 4];
            float4 v0 = *(const float4*)&Vs[kk][cg * 8];
            float4 v1 = *(const float4*)&Vs[kk][cg * 8 + 4];
            float av[4] = {a.x, a.y, a.z, a.w};
            float wv[8] = {w0.x, w0.y, w0.z, w0.w, w1.x, w1.y, w1.z, w1.w};
            float vv[8] = {v0.x, v0.y, v0.z, v0.w, v1.x, v1.y, v1.z, v1.w};
#pragma unroll
            for (int r = 0; r < 4; ++r)
#pragma unroll
                for (int c = 0; c < 8; ++c) {
                    accP[r][c] += av[r] * wv[c];
                    accS[r][c] += av[r] * vv[c];
                }
        }
    }
#pragma unroll
    for (int r = 0; r < 4; ++r) {
        int row = row0 + rg * 4 + r;
        if (row < N) {
            float4 p0 = make_float4(accP[r][0], accP[r][1], accP[r][2], accP[r][3]);
            float4 p1 = make_float4(accP[r][4], accP[r][5], accP[r][6], accP[r][7]);
            float4 s0 = make_float4(accS[r][0], accS[r][1], accS[r][2], accS[r][3]);
            float4 s1 = make_float4(accS[r][4], accS[r][5], accS[r][6], accS[r][7]);
            ((float4*)outP)[(size_t)row * 32 + cg * 2] = p0;
            ((float4*)outP)[(size_t)row * 32 + cg * 2 + 1] = p1;
            ((float4*)outS)[(size_t)row * 32 + cg * 2] = s0;
            ((float4*)outS)[(size_t)row * 32 + cg * 2 + 1] = s1;
        }
    }
}

// ------------- pack h_proj channels (c, c+64) into one bf16x2 dword -------------
__global__ __launch_bounds__(256) void pack_k(const float* __restrict__ hp,
                                              unsigned* __restrict__ hp_pk, int N) {
    int idx = blockIdx.x * 256 + threadIdx.x;
    if (idx >= N * 64) return;
    int n = idx >> 6, c = idx & 63;
    float x0 = hp[(size_t)n * DIM + c];
    float x1 = hp[(size_t)n * DIM + c + 64];
    hp_pk[idx] = bf16rne(x0) | (bf16rne(x1) << 16);
}

// ------------- per-node per-head attention scalars (4 tables, N*4) -------------
__global__ __launch_bounds__(256) void node_dots_k(const float* __restrict__ hp,
                                                   const float* __restrict__ a_in,
                                                   const float* __restrict__ a_out,
                                                   float* __restrict__ pA0, float* __restrict__ pA1,
                                                   float* __restrict__ pB0, float* __restrict__ pB1,
                                                   int N) {
    int idx = blockIdx.x * 256 + threadIdx.x;
    if (idx >= N * HEADS) return;
    int n = idx >> 2, hh = idx & 3;
    const float4* v4 = (const float4*)(hp + (size_t)n * DIM + hh * HD);
    const float4* ai = (const float4*)(a_in + hh * 2 * HD);
    const float4* ao = (const float4*)(a_out + hh * 2 * HD);
    float s0 = 0.f, s1 = 0.f, s2 = 0.f, s3 = 0.f;
#pragma unroll
    for (int i = 0; i < 8; ++i) {
        float4 v = v4[i];
        float4 x0 = ai[i], x1 = ai[8 + i], y0 = ao[i], y1 = ao[8 + i];
        s0 += v.x * x0.x + v.y * x0.y + v.z * x0.z + v.w * x0.w;
        s1 += v.x * x1.x + v.y * x1.y + v.z * x1.z + v.w * x1.w;
        s2 += v.x * y0.x + v.y * y0.y + v.z * y0.z + v.w * y0.w;
        s3 += v.x * y1.x + v.y * y1.y + v.z * y1.z + v.w * y1.w;
    }
    pA0[idx] = s0; pA1[idx] = s1; pB0[idx] = s2; pB1[idx] = s3;
}

// ---------------- bucketed CSR build (8 segments / bucket) ----------------
// Segment = receiver d (in-dir) or N+s (out-dir). Bucket = seg >> 3.

__global__ __launch_bounds__(256) void bcnt_k(const int* __restrict__ ei, int* __restrict__ bcnt,
                                              int E, int N) {
    int e = blockIdx.x * 256 + threadIdx.x;
    if (e >= E) return;
    int s = ei[e], d = ei[E + e];
    atomicAdd(&bcnt[d >> 3], 1);
    atomicAdd(&bcnt[(N + s) >> 3], 1);
}

// hierarchical exclusive scan of bcnt[NB] -> boff[NB+1]
__global__ __launch_bounds__(256) void scan1_k(const int* __restrict__ bcnt, int* __restrict__ boff,
                                               int* __restrict__ bs, int NB) {
    __shared__ int ls[256];
    int t = threadIdx.x;
    int i = blockIdx.x * 256 + t;
    int v = (i < NB) ? bcnt[i] : 0;
    ls[t] = v;
    __syncthreads();
#pragma unroll
    for (int d = 1; d < 256; d <<= 1) {
        int u = (t >= d) ? ls[t - d] : 0;
        __syncthreads();
        ls[t] += u;
        __syncthreads();
    }
    if (i < NB) boff[i + 1] = ls[t];
    if (t == 255) bs[blockIdx.x] = ls[255];
}

__global__ __launch_bounds__(256) void scan2_k(const int* __restrict__ bs, int* __restrict__ bo, int B) {
    __shared__ int ls[256];
    int t = threadIdx.x;
    int per = (B + 255) / 256;
    int b0 = t * per, b1 = min(b0 + per, B);
    int sum = 0;
    for (int j = b0; j < b1; ++j) sum += bs[j];
    ls[t] = sum;
    __syncthreads();
#pragma unroll
    for (int d = 1; d < 256; d <<= 1) {
        int u = (t >= d) ? ls[t - d] : 0;
        __syncthreads();
        ls[t] += u;
        __syncthreads();
    }
    int base = (t == 0) ? 0 : ls[t - 1];
    for (int j = b0; j < b1; ++j) { bo[j] = base; base += bs[j]; }
}

__global__ __launch_bounds__(256) void scan3_k(int* __restrict__ boff, const int* __restrict__ bo, int NB) {
    int i = blockIdx.x * 256 + threadIdx.x;
    if (i < NB) boff[i + 1] += bo[blockIdx.x];
    if (i == 0) boff[0] = 0;
}

// partition: rec[p] = sender | (seg_local << 20); positions sequential per bucket
__global__ __launch_bounds__(256) void part_k(const int* __restrict__ ei, int* __restrict__ bcur,
                                              unsigned* __restrict__ rec, int E, int N) {
    int e = blockIdx.x * 256 + threadIdx.x;
    if (e >= E) return;
    int s = ei[e], d = ei[E + e];
    int p = atomicAdd(&bcur[d >> 3], 1);
    rec[p] = (unsigned)s | ((unsigned)(d & 7) << 20);
    int so = N + s;
    int q = atomicAdd(&bcur[so >> 3], 1);
    rec[q] = (unsigned)d | ((unsigned)(so & 7) << 20);
}

// per-bucket: 8-seg LDS count -> scan -> write off[] and csr[]
__global__ __launch_bounds__(256) void build_k(const unsigned* __restrict__ rec,
                                               const int* __restrict__ boff,
                                               int* __restrict__ off, int* __restrict__ csr,
                                               int M, int twoE, int NB) {
    __shared__ int lcnt[SEGS_PER_BKT];
    __shared__ int lbase[SEGS_PER_BKT];
    __shared__ int lcur[SEGS_PER_BKT];
    const int b = blockIdx.x;
    const int t = threadIdx.x;
    const int base = boff[b];
    const int cnt = boff[b + 1] - base;
    const int seg0 = b * SEGS_PER_BKT;
    if (t < SEGS_PER_BKT) lcnt[t] = 0;
    __syncthreads();
    for (int k = t; k < cnt; k += 256) atomicAdd(&lcnt[rec[base + k] >> 20], 1);
    __syncthreads();
    if (t == 0) {
        int run = 0;
#pragma unroll
        for (int i = 0; i < SEGS_PER_BKT; ++i) { lbase[i] = run; lcur[i] = run; run += lcnt[i]; }
    }
    __syncthreads();
    if (t < SEGS_PER_BKT) {
        int seg = seg0 + t;
        if (seg < M) off[seg] = base + lbase[t];
    }
    if (b == NB - 1 && t == 0) off[M] = twoE;
    __syncthreads();
    for (int k = t; k < cnt; k += 256) {
        unsigned r = rec[base + k];
        int pos = atomicAdd(&lcur[r >> 20], 1);
        csr[base + pos] = (int)(r & 0xFFFFFu);
    }
}

// ---------------- fused: per-node softmax-aggregate (both dirs) + combine + LN ----------------
__global__ __launch_bounds__(256) void node_aggr_ln_k(const unsigned* __restrict__ hp_pk,
                                                      const float* __restrict__ h_self,
                                                      const float* __restrict__ pA0, const float* __restrict__ pA1,
                                                      const float* __restrict__ pB0, const float* __restrict__ pB1,
                                                      const int* __restrict__ off, const int* __restrict__ csr,
                                                      const float* __restrict__ bias,
                                                      const float* __restrict__ gamma,
                                                      const float* __restrict__ beta,
                                                      float* __restrict__ out, int N) {
    int wave = threadIdx.x >> 6;
    int lane = threadIdx.x & 63;
    int n = blockIdx.x * 4 + wave;
    if (n >= N) return;
    const int hsel = lane >> 5;

    float acc0 = 0.f, acc1 = 0.f;

#pragma unroll
    for (int dir = 0; dir < 2; ++dir) {
        const int seg = (dir == 0) ? n : N + n;
        const int beg = off[seg], end = off[seg + 1];
        const int len = end - beg;
        if (len == 0) continue;
        const float* __restrict__ p0 = (dir == 0) ? pA0 : pB0;
        const float* __restrict__ p1 = (dir == 0) ? pA1 : pB1;
        float4 r1 = ((const float4*)p1)[n];

        if (len <= 64) {
            int sid = 0;
            float e0 = -INFINITY, e1 = -INFINITY, e2 = -INFINITY, e3 = -INFINITY;
            if (lane < len) {
                sid = csr[beg + lane];
                float4 r0 = ((const float4*)p0)[sid];
                e0 = lrelu(r0.x + r1.x);
                e1 = lrelu(r0.y + r1.y);
                e2 = lrelu(r0.z + r1.z);
                e3 = lrelu(r0.w + r1.w);
            }
            float m0 = e0, m1 = e1, m2 = e2, m3 = e3;
#pragma unroll
            for (int d = 1; d < 64; d <<= 1) {
                m0 = fmaxf(m0, __shfl_xor(m0, d, 64));
                m1 = fmaxf(m1, __shfl_xor(m1, d, 64));
                m2 = fmaxf(m2, __shfl_xor(m2, d, 64));
                m3 = fmaxf(m3, __shfl_xor(m3, d, 64));
            }
            float w0 = 0.f, w1 = 0.f, w2 = 0.f, w3 = 0.f;
            if (lane < len) {
                w0 = expf(e0 - m0); w1 = expf(e1 - m1);
                w2 = expf(e2 - m2); w3 = expf(e3 - m3);
            }
            float s0 = w0, s1 = w1, s2 = w2, s3 = w3;
#pragma unroll
            for (int d = 1; d < 64; d <<= 1) {
                s0 += __shfl_xor(s0, d, 64);
                s1 += __shfl_xor(s1, d, 64);
                s2 += __shfl_xor(s2, d, 64);
                s3 += __shfl_xor(s3, d, 64);
            }
            w0 *= 1.f / (s0 + EPS_SM);
            w1 *= 1.f / (s1 + EPS_SM);
            w2 *= 1.f / (s2 + EPS_SM);
            w3 *= 1.f / (s3 + EPS_SM);

            if (len <= 32) {
                float t1 = __shfl_xor(w1, 32, 64);
                float t3 = __shfl_xor(w3, 32, 64);
                float uA = hsel ? t1 : w0;
                float uB = hsel ? t3 : w2;
                int src = (hsel << 5);
                for (int j = 0; j < len; ++j) {
                    int sj = __shfl(sid, j, 64);
                    float wa = __shfl(uA, j + src, 64);
                    float wb = __shfl(uB, j + src, 64);
                    unsigned pk = hp_pk[(size_t)sj * 64 + lane];
                    acc0 += wa * __uint_as_float(pk << 16);
                    acc1 += wb * __uint_as_float(pk & 0xffff0000u);
                }
            } else {
                for (int j = 0; j < len; ++j) {
                    int sj = __shfl(sid, j, 64);
                    float w0j = __shfl(w0, j, 64);
                    float w1j = __shfl(w1, j, 64);
                    float w2j = __shfl(w2, j, 64);
                    float w3j = __shfl(w3, j, 64);
                    float wa = hsel ? w1j : w0j;
                    float wb = hsel ? w3j : w2j;
                    unsigned pk = hp_pk[(size_t)sj * 64 + lane];
                    acc0 += wa * __uint_as_float(pk << 16);
                    acc1 += wb * __uint_as_float(pk & 0xffff0000u);
                }
            }
        } else {
            float m0 = -INFINITY, m1 = -INFINITY, m2 = -INFINITY, m3 = -INFINITY;
            for (int base = beg; base < end; base += 64) {
                int j = base + lane;
                if (j < end) {
                    int sid = csr[j];
                    float4 r0 = ((const float4*)p0)[sid];
                    m0 = fmaxf(m0, lrelu(r0.x + r1.x));
                    m1 = fmaxf(m1, lrelu(r0.y + r1.y));
                    m2 = fmaxf(m2, lrelu(r0.z + r1.z));
                    m3 = fmaxf(m3, lrelu(r0.w + r1.w));
                }
            }
#pragma unroll
            for (int d = 1; d < 64; d <<= 1) {
                m0 = fmaxf(m0, __shfl_xor(m0, d, 64));
                m1 = fmaxf(m1, __shfl_xor(m1, d, 64));
                m2 = fmaxf(m2, __shfl_xor(m2, d, 64));
                m3 = fmaxf(m3, __shfl_xor(m3, d, 64));
            }
            float s0 = 0.f, s1 = 0.f, s2 = 0.f, s3 = 0.f;
            for (int base = beg; base < end; base += 64) {
                int j = base + lane;
                if (j < end) {
                    int sid = csr[j];
                    float4 r0 = ((const float4*)p0)[sid];
                    s0 += expf(lrelu(r0.x + r1.x) - m0);
                    s1 += expf(lrelu(r0.y + r1.y) - m1);
                    s2 += expf(lrelu(r0.z + r1.z) - m2);
                    s3 += expf(lrelu(r0.w + r1.w) - m3);
                }
            }
#pragma unroll
            for (int d = 1; d < 64; d <<= 1) {
                s0 += __shfl_xor(s0, d, 64);
                s1 += __shfl_xor(s1, d, 64);
                s2 += __shfl_xor(s2, d, 64);
                s3 += __shfl_xor(s3, d, 64);
            }
            const float is0 = 1.f / (s0 + EPS_SM);
            const float is1 = 1.f / (s1 + EPS_SM);
            const float is2 = 1.f / (s2 + EPS_SM);
            const float is3 = 1.f / (s3 + EPS_SM);
            for (int base = beg; base < end; base += 64) {
                int cnt = min(64, end - base);
                int sid = 0;
                float w0 = 0.f, w1 = 0.f, w2 = 0.f, w3 = 0.f;
                if (lane < cnt) {
                    sid = csr[base + lane];
                    float4 r0 = ((const float4*)p0)[sid];
                    w0 = expf(lrelu(r0.x + r1.x) - m0) * is0;
                    w1 = expf(lrelu(r0.y + r1.y) - m1) * is1;
                    w2 = expf(lrelu(r0.z + r1.z) - m2) * is2;
                    w3 = expf(lrelu(r0.w + r1.w) - m3) * is3;
                }
                for (int j = 0; j < cnt; ++j) {
                    int sj = __shfl(sid, j, 64);
                    float w0j = __shfl(w0, j, 64);
                    float w1j = __shfl(w1, j, 64);
                    float w2j = __shfl(w2, j, 64);
                    float w3j = __shfl(w3, j, 64);
                    float wa = hsel ? w1j : w0j;
                    float wb = hsel ? w3j : w2j;
                    unsigned pk = hp_pk[(size_t)sj * 64 + lane];
                    acc0 += wa * __uint_as_float(pk << 16);
                    acc1 += wb * __uint_as_float(pk & 0xffff0000u);
                }
            }
        }
    }

    size_t bb = (size_t)n * DIM;
    float x0 = h_self[bb + lane] + acc0 + bias[lane];
    float x1 = h_self[bb + lane + 64] + acc1 + bias[lane + 64];
    float sum = x0 + x1, sq = x0 * x0 + x1 * x1;
#pragma unroll
    for (int m = 1; m < 64; m <<= 1) {
        sum += __shfl_xor(sum, m, 64);
        sq += __shfl_xor(sq, m, 64);
    }
    float mean = sum * (1.f / 128.f);
    float var = sq * (1.f / 128.f) - mean * mean;
    float inv = rsqrtf(var + EPS_LN);
    out[bb + lane] = (x0 - mean) * inv * gamma[lane] + beta[lane];
    out[bb + lane + 64] = (x1 - mean) * inv * gamma[lane + 64] + beta[lane + 64];
}

extern "C" void kernel_launch(void* const* d_in, const int* in_sizes, int n_in,
                              void* d_out, int out_size, void* d_ws, size_t ws_size,
                              hipStream_t stream) {
    const float* h      = (const float*)d_in[0];
    const int*   ei     = (const int*)d_in[1];
    const float* W      = (const float*)d_in[2];
    const float* W_self = (const float*)d_in[3];
    const float* a_in   = (const float*)d_in[4];
    const float* a_out  = (const float*)d_in[5];
    const float* bias   = (const float*)d_in[6];
    const float* gamma  = (const float*)d_in[7];
    const float* beta   = (const float*)d_in[8];
    float* out = (float*)d_out;

    const int N = in_sizes[0] / DIM;
    const int E = in_sizes[1] / 2;
    const int M = 2 * N;
    const int NB = (M + SEGS_PER_BKT - 1) / SEGS_PER_BKT;   // buckets
    const int SB = (NB + 255) / 256;                        // scan blocks
    const int twoE = 2 * E;

    // workspace layout
    float* ws = (float*)d_ws;
    size_t off_f = 0;
    float* h_proj = ws + off_f; off_f += (size_t)N * DIM;
    float* h_self = ws + off_f; off_f += (size_t)N * DIM;
    unsigned* hp_pk = (unsigned*)(ws + off_f); off_f += (size_t)N * 64;
    float* pA0 = ws + off_f; off_f += (size_t)N * 4;
    float* pA1 = ws + off_f; off_f += (size_t)N * 4;
    float* pB0 = ws + off_f; off_f += (size_t)N * 4;
    float* pB1 = ws + off_f; off_f += (size_t)N * 4;
    int* ip = (int*)(ws + off_f);
    size_t off_i = 0;
    int* bcnt  = ip + off_i; off_i += NB;
    int* boff  = ip + off_i; off_i += (size_t)NB + 1;
    int* bcur  = ip + off_i; off_i += NB;
    int* bs    = ip + off_i; off_i += SB;
    int* bo    = ip + off_i; off_i += SB;
    int* off   = ip + off_i; off_i += (size_t)M + 1;
    unsigned* rec = (unsigned*)(ip + off_i); off_i += (size_t)twoE;
    int* csr   = ip + off_i; off_i += (size_t)twoE;

    // ---- bucketed CSR build ----
    hipMemsetAsync(bcnt, 0, (size_t)NB * sizeof(int), stream);
    int eblocks = (E + 255) / 256;
    bcnt_k<<<eblocks, 256, 0, stream>>>(ei, bcnt, E, N);
    scan1_k<<<SB, 256, 0, stream>>>(bcnt, boff, bs, NB);
    scan2_k<<<1, 256, 0, stream>>>(bs, bo, SB);
    scan3_k<<<SB, 256, 0, stream>>>(boff, bo, NB);
    hipMemcpyAsync(bcur, boff, (size_t)NB * sizeof(int), hipMemcpyDeviceToDevice, stream);
    part_k<<<eblocks, 256, 0, stream>>>(ei, bcur, rec, E, N);
    build_k<<<NB, 256, 0, stream>>>(rec, boff, off, csr, M, twoE, NB);

    // ---- projections ----
    dual_gemm_k<<<(N + GROWS - 1) / GROWS, 256, 0, stream>>>(h, W, W_self, h_proj, h_self, N);
    node_dots_k<<<(N * 4 + 255) / 256, 256, 0, stream>>>(h_proj, a_in, a_out, pA0, pA1, pB0, pB1, N);
    pack_k<<<(N * 64 + 255) / 256, 256, 0, stream>>>(h_proj, hp_pk, N);

    // ---- fused aggregate + LN ----
    node_aggr_ln_k<<<(N + 3) / 4, 256, 0, stream>>>(hp_pk, h_self, pA0, pA1, pB0, pB1,
                                                    off, csr, bias, gamma, beta, out, N);
}

// Round 6
// 601.946 us; speedup vs baseline: 2.0462x; 1.5895x over previous
//
#include <hip/hip_runtime.h>
#include <math.h>

#define HEADS 4
#define HD 32
#define DIM 128
#define NEG_SLOPE 0.2f
#define EPS_SM 1e-8f
#define EPS_LN 1e-5f
#define GROWS 64
#define SH1 9              // 512 segments per coarse bin; NBIN = ceil(2N/512) = 391 <= 512
#define PB 128             // partition blocks (reservation chain depth)

__device__ __forceinline__ float lrelu(float x) { return x > 0.f ? x : NEG_SLOPE * x; }
__device__ __forceinline__ unsigned bf16rne(float x) {
    unsigned b = __float_as_uint(x);
    return (b + 0x7fffu + ((b >> 16) & 1u)) >> 16;
}

// ---------------- fused dual GEMM: h@W -> outP, h@W_self -> outS ----------------
__global__ __launch_bounds__(256) void dual_gemm_k(const float* __restrict__ h,
                                                   const float* __restrict__ W,
                                                   const float* __restrict__ V,
                                                   float* __restrict__ outP,
                                                   float* __restrict__ outS, int N) {
    __shared__ float As[32][GROWS];
    __shared__ float Ws[32][DIM];
    __shared__ float Vs[32][DIM];
    const int tid = threadIdx.x;
    const int cg = tid & 15;
    const int rg = tid >> 4;
    const int row0 = blockIdx.x * GROWS;

    float accP[4][8], accS[4][8];
#pragma unroll
    for (int r = 0; r < 4; ++r)
#pragma unroll
        for (int c = 0; c < 8; ++c) { accP[r][c] = 0.f; accS[r][c] = 0.f; }

    for (int kc = 0; kc < 4; ++kc) {
        __syncthreads();
#pragma unroll
        for (int p = 0; p < 2; ++p) {
            int f = tid + p * 256;
            int r = f >> 3, c4 = f & 7;
            float4 v = make_float4(0.f, 0.f, 0.f, 0.f);
            if (row0 + r < N) v = ((const float4*)h)[(size_t)(row0 + r) * 32 + kc * 8 + c4];
            As[c4 * 4 + 0][r] = v.x;
            As[c4 * 4 + 1][r] = v.y;
            As[c4 * 4 + 2][r] = v.z;
            As[c4 * 4 + 3][r] = v.w;
        }
#pragma unroll
        for (int p = 0; p < 4; ++p) {
            int f = tid + p * 256;
            int lk = f >> 5, c4 = f & 31;
            ((float4*)&Ws[lk][0])[c4] = ((const float4*)W)[(size_t)(kc * 32 + lk) * 32 + c4];
            ((float4*)&Vs[lk][0])[c4] = ((const float4*)V)[(size_t)(kc * 32 + lk) * 32 + c4];
        }
        __syncthreads();
#pragma unroll
        for (int kk = 0; kk < 32; ++kk) {
            float4 a = *(const float4*)&As[kk][rg * 4];
            float4 w0 = *(const float4*)&Ws[kk][cg * 8];
            float4 w1 = *(const float4*)&Ws[kk][cg * 8 + 4];
            float4 v0 = *(const float4*)&Vs[kk][cg * 8];
            float4 v1 = *(const float4*)&Vs[kk][cg * 8 + 4];
            float av[4] = {a.x, a.y, a.z, a.w};
            float wv[8] = {w0.x, w0.y, w0.z, w0.w, w1.x, w1.y, w1.z, w1.w};
            float vv[8] = {v0.x, v0.y, v0.z, v0.w, v1.x, v1.y, v1.z, v1.w};
#pragma unroll
            for (int r = 0; r < 4; ++r)
#pragma unroll
                for (int c = 0; c < 8; ++c) {
                    accP[r][c] += av[r] * wv[c];
                    accS[r][c] += av[r] * vv[c];
                }
        }
    }
#pragma unroll
    for (int r = 0; r < 4; ++r) {
        int row = row0 + rg * 4 + r;
        if (row < N) {
            float4 p0 = make_float4(accP[r][0], accP[r][1], accP[r][2], accP[r][3]);
            float4 p1 = make_float4(accP[r][4], accP[r][5], accP[r][6], accP[r][7]);
            float4 s0 = make_float4(accS[r][0], accS[r][1], accS[r][2], accS[r][3]);
            float4 s1 = make_float4(accS[r][4], accS[r][5], accS[r][6], accS[r][7]);
            ((float4*)outP)[(size_t)row * 32 + cg * 2] = p0;
            ((float4*)outP)[(size_t)row * 32 + cg * 2 + 1] = p1;
            ((float4*)outS)[(size_t)row * 32 + cg * 2] = s0;
            ((float4*)outS)[(size_t)row * 32 + cg * 2 + 1] = s1;
        }
    }
}

// ------------- pack h_proj channels (c, c+64) into one bf16x2 dword -------------
__global__ __launch_bounds__(256) void pack_k(const float* __restrict__ hp,
                                              unsigned* __restrict__ hp_pk, int N) {
    int idx = blockIdx.x * 256 + threadIdx.x;
    if (idx >= N * 64) return;
    int n = idx >> 6, c = idx & 63;
    float x0 = hp[(size_t)n * DIM + c];
    float x1 = hp[(size_t)n * DIM + c + 64];
    hp_pk[idx] = bf16rne(x0) | (bf16rne(x1) << 16);
}

// ------------- per-node per-head attention scalars (4 tables, N*4) -------------
__global__ __launch_bounds__(256) void node_dots_k(const float* __restrict__ hp,
                                                   const float* __restrict__ a_in,
                                                   const float* __restrict__ a_out,
                                                   float* __restrict__ pA0, float* __restrict__ pA1,
                                                   float* __restrict__ pB0, float* __restrict__ pB1,
                                                   int N) {
    int idx = blockIdx.x * 256 + threadIdx.x;
    if (idx >= N * HEADS) return;
    int n = idx >> 2, hh = idx & 3;
    const float4* v4 = (const float4*)(hp + (size_t)n * DIM + hh * HD);
    const float4* ai = (const float4*)(a_in + hh * 2 * HD);
    const float4* ao = (const float4*)(a_out + hh * 2 * HD);
    float s0 = 0.f, s1 = 0.f, s2 = 0.f, s3 = 0.f;
#pragma unroll
    for (int i = 0; i < 8; ++i) {
        float4 v = v4[i];
        float4 x0 = ai[i], x1 = ai[8 + i], y0 = ao[i], y1 = ao[8 + i];
        s0 += v.x * x0.x + v.y * x0.y + v.z * x0.z + v.w * x0.w;
        s1 += v.x * x1.x + v.y * x1.y + v.z * x1.z + v.w * x1.w;
        s2 += v.x * y0.x + v.y * y0.y + v.z * y0.z + v.w * y0.w;
        s3 += v.x * y1.x + v.y * y1.y + v.z * y1.z + v.w * y1.w;
    }
    pA0[idx] = s0; pA1[idx] = s1; pB0[idx] = s2; pB1[idx] = s3;
}

// ---------------- two-level CSR build ----------------
// Segment = receiver d (in-dir) or N+s (out-dir). Coarse bin = seg >> SH1 (<=512 bins).

__global__ __launch_bounds__(256) void bcnt1_k(const int* __restrict__ ei, int* __restrict__ bcnt,
                                               int E, int N, int NBIN) {
    __shared__ int lh[512];
    const int t = threadIdx.x;
    for (int i = t; i < 512; i += 256) lh[i] = 0;
    __syncthreads();
    for (int e = blockIdx.x * 256 + t; e < E; e += gridDim.x * 256) {
        int s = ei[e], d = ei[E + e];
        atomicAdd(&lh[d >> SH1], 1);
        atomicAdd(&lh[(N + s) >> SH1], 1);
    }
    __syncthreads();
    for (int i = t; i < NBIN; i += 256) {
        int v = lh[i];
        if (v) atomicAdd(&bcnt[i], v);
    }
}

// single-block exclusive scan over NBIN (<=512) bins -> bbase[NBIN+1], bcur init
__global__ __launch_bounds__(256) void bscan1_k(const int* __restrict__ bcnt,
                                                int* __restrict__ bbase, int* __restrict__ bcur,
                                                int NBIN, int twoE) {
    __shared__ int ls[256];
    int t = threadIdx.x;
    int i0 = 2 * t, i1 = 2 * t + 1;
    int v0 = (i0 < NBIN) ? bcnt[i0] : 0;
    int v1 = (i1 < NBIN) ? bcnt[i1] : 0;
    int pair = v0 + v1;
    ls[t] = pair;
    __syncthreads();
#pragma unroll
    for (int d = 1; d < 256; d <<= 1) {
        int u = (t >= d) ? ls[t - d] : 0;
        __syncthreads();
        ls[t] += u;
        __syncthreads();
    }
    int excl = ls[t] - pair;
    if (i0 < NBIN) { bbase[i0] = excl; bcur[i0] = excl; }
    if (i1 < NBIN) { bbase[i1] = excl + v0; bcur[i1] = excl + v0; }
    if (t == 0) bbase[NBIN] = twoE;
}

// partition into coarse bins with block-bulk reservations (write-combined runs)
__global__ __launch_bounds__(256) void part1_k(const int* __restrict__ ei, int* __restrict__ bcur,
                                               unsigned* __restrict__ rec, int E, int N) {
    __shared__ int lcnt[512];
    __shared__ int gbase[512];
    const int t = threadIdx.x;
    const int CH = (E + gridDim.x - 1) / gridDim.x;
    const int e0 = blockIdx.x * CH;
    const int e1 = min(e0 + CH, E);
    for (int i = t; i < 512; i += 256) lcnt[i] = 0;
    __syncthreads();
    // phase A: count this chunk's records per bin
    for (int e = e0 + t; e < e1; e += 256) {
        int s = ei[e], d = ei[E + e];
        atomicAdd(&lcnt[d >> SH1], 1);
        atomicAdd(&lcnt[(N + s) >> SH1], 1);
    }
    __syncthreads();
    // reserve contiguous global runs per bin; reuse lcnt as local rank cursor
    for (int i = t; i < 512; i += 256) {
        int c = lcnt[i];
        gbase[i] = (c > 0) ? atomicAdd(&bcur[i], c) : 0;
        lcnt[i] = 0;
    }
    __syncthreads();
    // phase B: re-read (L1/L2-hot) and emit records into the reserved runs
    for (int e = e0 + t; e < e1; e += 256) {
        int s = ei[e], d = ei[E + e];
        int b1 = d >> SH1;
        int r1 = atomicAdd(&lcnt[b1], 1);
        rec[gbase[b1] + r1] = (unsigned)s | ((unsigned)(d & 511) << 20);
        int so = N + s;
        int b2 = so >> SH1;
        int r2 = atomicAdd(&lcnt[b2], 1);
        rec[gbase[b2] + r2] = (unsigned)d | ((unsigned)(so & 511) << 20);
    }
}

// per-bin: 512-seg LDS histogram -> scan -> write off[] and csr[]
__global__ __launch_bounds__(256) void build2_k(const unsigned* __restrict__ rec,
                                                const int* __restrict__ bbase,
                                                int* __restrict__ off, int* __restrict__ csr,
                                                int M, int twoE, int NBIN) {
    __shared__ int lcnt[512];
    __shared__ int lcur[512];
    __shared__ int ls[256];
    const int b = blockIdx.x;
    const int t = threadIdx.x;
    const int base = bbase[b];
    const int cnt = bbase[b + 1] - base;
    const int seg0 = b << SH1;
    for (int i = t; i < 512; i += 256) lcnt[i] = 0;
    __syncthreads();
    for (int k = t; k < cnt; k += 256) atomicAdd(&lcnt[rec[base + k] >> 20], 1);
    __syncthreads();
    int v0 = lcnt[2 * t], v1 = lcnt[2 * t + 1];
    int pair = v0 + v1;
    ls[t] = pair;
    __syncthreads();
#pragma unroll
    for (int d = 1; d < 256; d <<= 1) {
        int u = (t >= d) ? ls[t - d] : 0;
        __syncthreads();
        ls[t] += u;
        __syncthreads();
    }
    int excl = ls[t] - pair;
    lcur[2 * t] = excl;
    lcur[2 * t + 1] = excl + v0;
    int sg = seg0 + 2 * t;
    if (sg < M) off[sg] = base + excl;
    if (sg + 1 < M) off[sg + 1] = base + excl + v0;
    if (b == NBIN - 1 && t == 0) off[M] = twoE;
    __syncthreads();
    for (int k = t; k < cnt; k += 256) {
        unsigned r = rec[base + k];
        int pos = atomicAdd(&lcur[r >> 20], 1);
        csr[base + pos] = (int)(r & 0xFFFFFu);
    }
}

// ---------------- fused: per-node softmax-aggregate (both dirs) + combine + LN ----------------
__global__ __launch_bounds__(256) void node_aggr_ln_k(const unsigned* __restrict__ hp_pk,
                                                      const float* __restrict__ h_self,
                                                      const float* __restrict__ pA0, const float* __restrict__ pA1,
                                                      const float* __restrict__ pB0, const float* __restrict__ pB1,
                                                      const int* __restrict__ off, const int* __restrict__ csr,
                                                      const float* __restrict__ bias,
                                                      const float* __restrict__ gamma,
                                                      const float* __restrict__ beta,
                                                      float* __restrict__ out, int N) {
    int wave = threadIdx.x >> 6;
    int lane = threadIdx.x & 63;
    int n = blockIdx.x * 4 + wave;
    if (n >= N) return;
    const int hsel = lane >> 5;

    float acc0 = 0.f, acc1 = 0.f;

#pragma unroll
    for (int dir = 0; dir < 2; ++dir) {
        const int seg = (dir == 0) ? n : N + n;
        const int beg = off[seg], end = off[seg + 1];
        const int len = end - beg;
        if (len == 0) continue;
        const float* __restrict__ p0 = (dir == 0) ? pA0 : pB0;
        const float* __restrict__ p1 = (dir == 0) ? pA1 : pB1;
        float4 r1 = ((const float4*)p1)[n];

        if (len <= 64) {
            int sid = 0;
            float e0 = -INFINITY, e1 = -INFINITY, e2 = -INFINITY, e3 = -INFINITY;
            if (lane < len) {
                sid = csr[beg + lane];
                float4 r0 = ((const float4*)p0)[sid];
                e0 = lrelu(r0.x + r1.x);
                e1 = lrelu(r0.y + r1.y);
                e2 = lrelu(r0.z + r1.z);
                e3 = lrelu(r0.w + r1.w);
            }
            float m0 = e0, m1 = e1, m2 = e2, m3 = e3;
#pragma unroll
            for (int d = 1; d < 64; d <<= 1) {
                m0 = fmaxf(m0, __shfl_xor(m0, d, 64));
                m1 = fmaxf(m1, __shfl_xor(m1, d, 64));
                m2 = fmaxf(m2, __shfl_xor(m2, d, 64));
                m3 = fmaxf(m3, __shfl_xor(m3, d, 64));
            }
            float w0 = 0.f, w1 = 0.f, w2 = 0.f, w3 = 0.f;
            if (lane < len) {
                w0 = expf(e0 - m0); w1 = expf(e1 - m1);
                w2 = expf(e2 - m2); w3 = expf(e3 - m3);
            }
            float s0 = w0, s1 = w1, s2 = w2, s3 = w3;
#pragma unroll
            for (int d = 1; d < 64; d <<= 1) {
                s0 += __shfl_xor(s0, d, 64);
                s1 += __shfl_xor(s1, d, 64);
                s2 += __shfl_xor(s2, d, 64);
                s3 += __shfl_xor(s3, d, 64);
            }
            w0 *= 1.f / (s0 + EPS_SM);
            w1 *= 1.f / (s1 + EPS_SM);
            w2 *= 1.f / (s2 + EPS_SM);
            w3 *= 1.f / (s3 + EPS_SM);

            if (len <= 32) {
                float t1 = __shfl_xor(w1, 32, 64);
                float t3 = __shfl_xor(w3, 32, 64);
                float uA = hsel ? t1 : w0;
                float uB = hsel ? t3 : w2;
                int src = (hsel << 5);
                for (int j = 0; j < len; ++j) {
                    int sj = __shfl(sid, j, 64);
                    float wa = __shfl(uA, j + src, 64);
                    float wb = __shfl(uB, j + src, 64);
                    unsigned pk = hp_pk[(size_t)sj * 64 + lane];
                    acc0 += wa * __uint_as_float(pk << 16);
                    acc1 += wb * __uint_as_float(pk & 0xffff0000u);
                }
            } else {
                for (int j = 0; j < len; ++j) {
                    int sj = __shfl(sid, j, 64);
                    float w0j = __shfl(w0, j, 64);
                    float w1j = __shfl(w1, j, 64);
                    float w2j = __shfl(w2, j, 64);
                    float w3j = __shfl(w3, j, 64);
                    float wa = hsel ? w1j : w0j;
                    float wb = hsel ? w3j : w2j;
                    unsigned pk = hp_pk[(size_t)sj * 64 + lane];
                    acc0 += wa * __uint_as_float(pk << 16);
                    acc1 += wb * __uint_as_float(pk & 0xffff0000u);
                }
            }
        } else {
            float m0 = -INFINITY, m1 = -INFINITY, m2 = -INFINITY, m3 = -INFINITY;
            for (int base = beg; base < end; base += 64) {
                int j = base + lane;
                if (j < end) {
                    int sid = csr[j];
                    float4 r0 = ((const float4*)p0)[sid];
                    m0 = fmaxf(m0, lrelu(r0.x + r1.x));
                    m1 = fmaxf(m1, lrelu(r0.y + r1.y));
                    m2 = fmaxf(m2, lrelu(r0.z + r1.z));
                    m3 = fmaxf(m3, lrelu(r0.w + r1.w));
                }
            }
#pragma unroll
            for (int d = 1; d < 64; d <<= 1) {
                m0 = fmaxf(m0, __shfl_xor(m0, d, 64));
                m1 = fmaxf(m1, __shfl_xor(m1, d, 64));
                m2 = fmaxf(m2, __shfl_xor(m2, d, 64));
                m3 = fmaxf(m3, __shfl_xor(m3, d, 64));
            }
            float s0 = 0.f, s1 = 0.f, s2 = 0.f, s3 = 0.f;
            for (int base = beg; base < end; base += 64) {
                int j = base + lane;
                if (j < end) {
                    int sid = csr[j];
                    float4 r0 = ((const float4*)p0)[sid];
                    s0 += expf(lrelu(r0.x + r1.x) - m0);
                    s1 += expf(lrelu(r0.y + r1.y) - m1);
                    s2 += expf(lrelu(r0.z + r1.z) - m2);
                    s3 += expf(lrelu(r0.w + r1.w) - m3);
                }
            }
#pragma unroll
            for (int d = 1; d < 64; d <<= 1) {
                s0 += __shfl_xor(s0, d, 64);
                s1 += __shfl_xor(s1, d, 64);
                s2 += __shfl_xor(s2, d, 64);
                s3 += __shfl_xor(s3, d, 64);
            }
            const float is0 = 1.f / (s0 + EPS_SM);
            const float is1 = 1.f / (s1 + EPS_SM);
            const float is2 = 1.f / (s2 + EPS_SM);
            const float is3 = 1.f / (s3 + EPS_SM);
            for (int base = beg; base < end; base += 64) {
                int cnt = min(64, end - base);
                int sid = 0;
                float w0 = 0.f, w1 = 0.f, w2 = 0.f, w3 = 0.f;
                if (lane < cnt) {
                    sid = csr[base + lane];
                    float4 r0 = ((const float4*)p0)[sid];
                    w0 = expf(lrelu(r0.x + r1.x) - m0) * is0;
                    w1 = expf(lrelu(r0.y + r1.y) - m1) * is1;
                    w2 = expf(lrelu(r0.z + r1.z) - m2) * is2;
                    w3 = expf(lrelu(r0.w + r1.w) - m3) * is3;
                }
                for (int j = 0; j < cnt; ++j) {
                    int sj = __shfl(sid, j, 64);
                    float w0j = __shfl(w0, j, 64);
                    float w1j = __shfl(w1, j, 64);
                    float w2j = __shfl(w2, j, 64);
                    float w3j = __shfl(w3, j, 64);
                    float wa = hsel ? w1j : w0j;
                    float wb = hsel ? w3j : w2j;
                    unsigned pk = hp_pk[(size_t)sj * 64 + lane];
                    acc0 += wa * __uint_as_float(pk << 16);
                    acc1 += wb * __uint_as_float(pk & 0xffff0000u);
                }
            }
        }
    }

    size_t bb = (size_t)n * DIM;
    float x0 = h_self[bb + lane] + acc0 + bias[lane];
    float x1 = h_self[bb + lane + 64] + acc1 + bias[lane + 64];
    float sum = x0 + x1, sq = x0 * x0 + x1 * x1;
#pragma unroll
    for (int m = 1; m < 64; m <<= 1) {
        sum += __shfl_xor(sum, m, 64);
        sq += __shfl_xor(sq, m, 64);
    }
    float mean = sum * (1.f / 128.f);
    float var = sq * (1.f / 128.f) - mean * mean;
    float inv = rsqrtf(var + EPS_LN);
    out[bb + lane] = (x0 - mean) * inv * gamma[lane] + beta[lane];
    out[bb + lane + 64] = (x1 - mean) * inv * gamma[lane + 64] + beta[lane + 64];
}

extern "C" void kernel_launch(void* const* d_in, const int* in_sizes, int n_in,
                              void* d_out, int out_size, void* d_ws, size_t ws_size,
                              hipStream_t stream) {
    const float* h      = (const float*)d_in[0];
    const int*   ei     = (const int*)d_in[1];
    const float* W      = (const float*)d_in[2];
    const float* W_self = (const float*)d_in[3];
    const float* a_in   = (const float*)d_in[4];
    const float* a_out  = (const float*)d_in[5];
    const float* bias   = (const float*)d_in[6];
    const float* gamma  = (const float*)d_in[7];
    const float* beta   = (const float*)d_in[8];
    float* out = (float*)d_out;

    const int N = in_sizes[0] / DIM;
    const int E = in_sizes[1] / 2;
    const int M = 2 * N;
    const int NBIN = (M + (1 << SH1) - 1) >> SH1;   // 391 for N=100K; must be <= 512
    const int twoE = 2 * E;

    // workspace layout
    float* ws = (float*)d_ws;
    size_t off_f = 0;
    float* h_proj = ws + off_f; off_f += (size_t)N * DIM;
    float* h_self = ws + off_f; off_f += (size_t)N * DIM;
    unsigned* hp_pk = (unsigned*)(ws + off_f); off_f += (size_t)N * 64;
    float* pA0 = ws + off_f; off_f += (size_t)N * 4;
    float* pA1 = ws + off_f; off_f += (size_t)N * 4;
    float* pB0 = ws + off_f; off_f += (size_t)N * 4;
    float* pB1 = ws + off_f; off_f += (size_t)N * 4;
    int* ip = (int*)(ws + off_f);
    size_t off_i = 0;
    int* bcnt  = ip + off_i; off_i += NBIN;
    int* bbase = ip + off_i; off_i += (size_t)NBIN + 1;
    int* bcur  = ip + off_i; off_i += NBIN;
    int* off   = ip + off_i; off_i += (size_t)M + 1;
    unsigned* rec = (unsigned*)(ip + off_i); off_i += (size_t)twoE;
    int* csr   = ip + off_i; off_i += (size_t)twoE;

    // ---- two-level CSR build ----
    hipMemsetAsync(bcnt, 0, (size_t)NBIN * sizeof(int), stream);
    bcnt1_k<<<256, 256, 0, stream>>>(ei, bcnt, E, N, NBIN);
    bscan1_k<<<1, 256, 0, stream>>>(bcnt, bbase, bcur, NBIN, twoE);
    part1_k<<<PB, 256, 0, stream>>>(ei, bcur, rec, E, N);
    build2_k<<<NBIN, 256, 0, stream>>>(rec, bbase, off, csr, M, twoE, NBIN);

    // ---- projections ----
    dual_gemm_k<<<(N + GROWS - 1) / GROWS, 256, 0, stream>>>(h, W, W_self, h_proj, h_self, N);
    node_dots_k<<<(N * 4 + 255) / 256, 256, 0, stream>>>(h_proj, a_in, a_out, pA0, pA1, pB0, pB1, N);
    pack_k<<<(N * 64 + 255) / 256, 256, 0, stream>>>(h_proj, hp_pk, N);

    // ---- fused aggregate + LN ----
    node_aggr_ln_k<<<(N + 3) / 4, 256, 0, stream>>>(hp_pk, h_self, pA0, pA1, pB0, pB1,
                                                    off, csr, bias, gamma, beta, out, N);
}

// Round 7
// 535.319 us; speedup vs baseline: 2.3009x; 1.1245x over previous
//
#include <hip/hip_runtime.h>
#include <math.h>

#define HEADS 4
#define HD 32
#define DIM 128
#define NEG_SLOPE 0.2f
#define EPS_SM 1e-8f
#define EPS_LN 1e-5f
#define GROWS 64
#define SH1 9              // 512 segments per coarse bin; NBIN = ceil(2N/512) <= 512
#define PB 128             // partition blocks (reservation chain depth)

__device__ __forceinline__ float lrelu(float x) { return x > 0.f ? x : NEG_SLOPE * x; }
__device__ __forceinline__ unsigned bf16rne(float x) {
    unsigned b = __float_as_uint(x);
    return (b + 0x7fffu + ((b >> 16) & 1u)) >> 16;
}

template<int LIM> __device__ __forceinline__ void rmax4(float& a, float& b, float& c, float& d) {
#pragma unroll
    for (int s = 1; s < LIM; s <<= 1) {
        a = fmaxf(a, __shfl_xor(a, s, 64));
        b = fmaxf(b, __shfl_xor(b, s, 64));
        c = fmaxf(c, __shfl_xor(c, s, 64));
        d = fmaxf(d, __shfl_xor(d, s, 64));
    }
}
template<int LIM> __device__ __forceinline__ void rsum4(float& a, float& b, float& c, float& d) {
#pragma unroll
    for (int s = 1; s < LIM; s <<= 1) {
        a += __shfl_xor(a, s, 64);
        b += __shfl_xor(b, s, 64);
        c += __shfl_xor(c, s, 64);
        d += __shfl_xor(d, s, 64);
    }
}

// ---------------- fused dual GEMM + attention dots + bf16 pack ----------------
// h@W -> (dots tables pA*/pB*, packed hp_pk);  h@W_self -> h_self (f32)
__global__ __launch_bounds__(256) void dual_gemm_k(const float* __restrict__ h,
                                                   const float* __restrict__ W,
                                                   const float* __restrict__ V,
                                                   const float* __restrict__ a_in,
                                                   const float* __restrict__ a_out,
                                                   float* __restrict__ h_self,
                                                   unsigned* __restrict__ hp_pk,
                                                   float* __restrict__ pA0, float* __restrict__ pA1,
                                                   float* __restrict__ pB0, float* __restrict__ pB1,
                                                   int N) {
    __shared__ float As[32][GROWS];
    __shared__ float Ws[32][DIM];
    __shared__ float Vs[32][DIM];
    __shared__ float ainL[256], aoutL[256];
    const int tid = threadIdx.x;
    const int cg = tid & 15;
    const int rg = tid >> 4;
    const int row0 = blockIdx.x * GROWS;

    ainL[tid] = a_in[tid];
    aoutL[tid] = a_out[tid];

    float accP[4][8], accS[4][8];
#pragma unroll
    for (int r = 0; r < 4; ++r)
#pragma unroll
        for (int c = 0; c < 8; ++c) { accP[r][c] = 0.f; accS[r][c] = 0.f; }

    for (int kc = 0; kc < 4; ++kc) {
        __syncthreads();
#pragma unroll
        for (int p = 0; p < 2; ++p) {
            int f = tid + p * 256;
            int r = f >> 3, c4 = f & 7;
            float4 v = make_float4(0.f, 0.f, 0.f, 0.f);
            if (row0 + r < N) v = ((const float4*)h)[(size_t)(row0 + r) * 32 + kc * 8 + c4];
            As[c4 * 4 + 0][r] = v.x;
            As[c4 * 4 + 1][r] = v.y;
            As[c4 * 4 + 2][r] = v.z;
            As[c4 * 4 + 3][r] = v.w;
        }
#pragma unroll
        for (int p = 0; p < 4; ++p) {
            int f = tid + p * 256;
            int lk = f >> 5, c4 = f & 31;
            ((float4*)&Ws[lk][0])[c4] = ((const float4*)W)[(size_t)(kc * 32 + lk) * 32 + c4];
            ((float4*)&Vs[lk][0])[c4] = ((const float4*)V)[(size_t)(kc * 32 + lk) * 32 + c4];
        }
        __syncthreads();
#pragma unroll
        for (int kk = 0; kk < 32; ++kk) {
            float4 a = *(const float4*)&As[kk][rg * 4];
            float4 w0 = *(const float4*)&Ws[kk][cg * 8];
            float4 w1 = *(const float4*)&Ws[kk][cg * 8 + 4];
            float4 v0 = *(const float4*)&Vs[kk][cg * 8];
            float4 v1 = *(const float4*)&Vs[kk][cg * 8 + 4];
            float av[4] = {a.x, a.y, a.z, a.w};
            float wv[8] = {w0.x, w0.y, w0.z, w0.w, w1.x, w1.y, w1.z, w1.w};
            float vv[8] = {v0.x, v0.y, v0.z, v0.w, v1.x, v1.y, v1.z, v1.w};
#pragma unroll
            for (int r = 0; r < 4; ++r)
#pragma unroll
                for (int c = 0; c < 8; ++c) {
                    accP[r][c] += av[r] * wv[c];
                    accS[r][c] += av[r] * vv[c];
                }
        }
    }

    // ---- epilogue 1: h_self (f32) ----
#pragma unroll
    for (int r = 0; r < 4; ++r) {
        int row = row0 + rg * 4 + r;
        if (row < N) {
            float4 s0 = make_float4(accS[r][0], accS[r][1], accS[r][2], accS[r][3]);
            float4 s1 = make_float4(accS[r][4], accS[r][5], accS[r][6], accS[r][7]);
            ((float4*)h_self)[(size_t)row * 32 + cg * 2] = s0;
            ((float4*)h_self)[(size_t)row * 32 + cg * 2 + 1] = s1;
        }
    }

    // ---- epilogue 2: attention dot tables (reduce 4 adjacent lanes) ----
    const int head = cg >> 2, qi = cg & 3;
#pragma unroll
    for (int r = 0; r < 4; ++r) {
        float d0 = 0.f, d1 = 0.f, d2 = 0.f, d3 = 0.f;
#pragma unroll
        for (int c = 0; c < 8; ++c) {
            float v = accP[r][c];
            int k = head * 64 + qi * 8 + c;
            d0 += v * ainL[k];
            d1 += v * ainL[k + 32];
            d2 += v * aoutL[k];
            d3 += v * aoutL[k + 32];
        }
        d0 += __shfl_xor(d0, 1, 64); d0 += __shfl_xor(d0, 2, 64);
        d1 += __shfl_xor(d1, 1, 64); d1 += __shfl_xor(d1, 2, 64);
        d2 += __shfl_xor(d2, 1, 64); d2 += __shfl_xor(d2, 2, 64);
        d3 += __shfl_xor(d3, 1, 64); d3 += __shfl_xor(d3, 2, 64);
        if (qi == 0) {
            int row = row0 + rg * 4 + r;
            if (row < N) {
                pA0[row * 4 + head] = d0;
                pA1[row * 4 + head] = d1;
                pB0[row * 4 + head] = d2;
                pB1[row * 4 + head] = d3;
            }
        }
    }

    // ---- epilogue 3: bf16 pack (c, c+64) via LDS half-exchange ----
    __syncthreads();                 // all waves done reading Ws
    float* lds2 = &Ws[0][0];         // 64 rows x 64 cols
    if (cg >= 8) {
#pragma unroll
        for (int r = 0; r < 4; ++r) {
            int rl = rg * 4 + r;
#pragma unroll
            for (int c = 0; c < 8; ++c) lds2[rl * 64 + (cg - 8) * 8 + c] = accP[r][c];
        }
    }
    __syncthreads();
    if (cg < 8) {
#pragma unroll
        for (int r = 0; r < 4; ++r) {
            int rl = rg * 4 + r;
            int row = row0 + rl;
            if (row < N) {
                unsigned pks[8];
#pragma unroll
                for (int c = 0; c < 8; ++c)
                    pks[c] = bf16rne(accP[r][c]) | (bf16rne(lds2[rl * 64 + cg * 8 + c]) << 16);
                uint4* dst = (uint4*)(hp_pk + (size_t)row * 64 + cg * 8);
                dst[0] = make_uint4(pks[0], pks[1], pks[2], pks[3]);
                dst[1] = make_uint4(pks[4], pks[5], pks[6], pks[7]);
            }
        }
    }
}

// ---------------- two-level CSR build ----------------
__global__ __launch_bounds__(256) void bcnt1_k(const int* __restrict__ ei, int* __restrict__ bcnt,
                                               int E, int N, int NBIN) {
    __shared__ int lh[512];
    const int t = threadIdx.x;
    for (int i = t; i < 512; i += 256) lh[i] = 0;
    __syncthreads();
    for (int e = blockIdx.x * 256 + t; e < E; e += gridDim.x * 256) {
        int s = ei[e], d = ei[E + e];
        atomicAdd(&lh[d >> SH1], 1);
        atomicAdd(&lh[(N + s) >> SH1], 1);
    }
    __syncthreads();
    for (int i = t; i < NBIN; i += 256) {
        int v = lh[i];
        if (v) atomicAdd(&bcnt[i], v);
    }
}

__global__ __launch_bounds__(256) void bscan1_k(const int* __restrict__ bcnt,
                                                int* __restrict__ bbase, int* __restrict__ bcur,
                                                int NBIN, int twoE) {
    __shared__ int ls[256];
    int t = threadIdx.x;
    int i0 = 2 * t, i1 = 2 * t + 1;
    int v0 = (i0 < NBIN) ? bcnt[i0] : 0;
    int v1 = (i1 < NBIN) ? bcnt[i1] : 0;
    int pair = v0 + v1;
    ls[t] = pair;
    __syncthreads();
#pragma unroll
    for (int d = 1; d < 256; d <<= 1) {
        int u = (t >= d) ? ls[t - d] : 0;
        __syncthreads();
        ls[t] += u;
        __syncthreads();
    }
    int excl = ls[t] - pair;
    if (i0 < NBIN) { bbase[i0] = excl; bcur[i0] = excl; }
    if (i1 < NBIN) { bbase[i1] = excl + v0; bcur[i1] = excl + v0; }
    if (t == 0) bbase[NBIN] = twoE;
}

__global__ __launch_bounds__(256) void part1_k(const int* __restrict__ ei, int* __restrict__ bcur,
                                               unsigned* __restrict__ rec, int E, int N) {
    __shared__ int lcnt[512];
    __shared__ int gbase[512];
    const int t = threadIdx.x;
    const int CH = (E + gridDim.x - 1) / gridDim.x;
    const int e0 = blockIdx.x * CH;
    const int e1 = min(e0 + CH, E);
    for (int i = t; i < 512; i += 256) lcnt[i] = 0;
    __syncthreads();
    for (int e = e0 + t; e < e1; e += 256) {
        int s = ei[e], d = ei[E + e];
        atomicAdd(&lcnt[d >> SH1], 1);
        atomicAdd(&lcnt[(N + s) >> SH1], 1);
    }
    __syncthreads();
    for (int i = t; i < 512; i += 256) {
        int c = lcnt[i];
        gbase[i] = (c > 0) ? atomicAdd(&bcur[i], c) : 0;
        lcnt[i] = 0;
    }
    __syncthreads();
    for (int e = e0 + t; e < e1; e += 256) {
        int s = ei[e], d = ei[E + e];
        int b1 = d >> SH1;
        int r1 = atomicAdd(&lcnt[b1], 1);
        rec[gbase[b1] + r1] = (unsigned)s | ((unsigned)(d & 511) << 20);
        int so = N + s;
        int b2 = so >> SH1;
        int r2 = atomicAdd(&lcnt[b2], 1);
        rec[gbase[b2] + r2] = (unsigned)d | ((unsigned)(so & 511) << 20);
    }
}

__global__ __launch_bounds__(256) void build2_k(const unsigned* __restrict__ rec,
                                                const int* __restrict__ bbase,
                                                int* __restrict__ off, int* __restrict__ csr,
                                                int M, int twoE, int NBIN) {
    __shared__ int lcnt[512];
    __shared__ int lcur[512];
    __shared__ int ls[256];
    const int b = blockIdx.x;
    const int t = threadIdx.x;
    const int base = bbase[b];
    const int cnt = bbase[b + 1] - base;
    const int seg0 = b << SH1;
    for (int i = t; i < 512; i += 256) lcnt[i] = 0;
    __syncthreads();
    for (int k = t; k < cnt; k += 256) atomicAdd(&lcnt[rec[base + k] >> 20], 1);
    __syncthreads();
    int v0 = lcnt[2 * t], v1 = lcnt[2 * t + 1];
    int pair = v0 + v1;
    ls[t] = pair;
    __syncthreads();
#pragma unroll
    for (int d = 1; d < 256; d <<= 1) {
        int u = (t >= d) ? ls[t - d] : 0;
        __syncthreads();
        ls[t] += u;
        __syncthreads();
    }
    int excl = ls[t] - pair;
    lcur[2 * t] = excl;
    lcur[2 * t + 1] = excl + v0;
    int sg = seg0 + 2 * t;
    if (sg < M) off[sg] = base + excl;
    if (sg + 1 < M) off[sg + 1] = base + excl + v0;
    if (b == NBIN - 1 && t == 0) off[M] = twoE;
    __syncthreads();
    for (int k = t; k < cnt; k += 256) {
        unsigned r = rec[base + k];
        int pos = atomicAdd(&lcur[r >> 20], 1);
        csr[base + pos] = (int)(r & 0xFFFFFu);
    }
}

// ---------------- fused: per-node softmax-aggregate (both dirs) + combine + LN ----------------
__global__ __launch_bounds__(256) void node_aggr_ln_k(const unsigned* __restrict__ hp_pk,
                                                      const float* __restrict__ h_self,
                                                      const float* __restrict__ pA0, const float* __restrict__ pA1,
                                                      const float* __restrict__ pB0, const float* __restrict__ pB1,
                                                      const int* __restrict__ off, const int* __restrict__ csr,
                                                      const float* __restrict__ bias,
                                                      const float* __restrict__ gamma,
                                                      const float* __restrict__ beta,
                                                      float* __restrict__ out, int N) {
    __shared__ float lw[4][64][4];   // per-wave: j -> (w0,w2,w1,w3)
    const int wave = threadIdx.x >> 6;
    const int lane = threadIdx.x & 63;
    const int n = blockIdx.x * 4 + wave;
    if (n >= N) return;
    const int hsel = lane >> 5;
    float* lwme = &lw[wave][lane][0];
    const float* lwv = &lw[wave][0][hsel * 2];   // element j at lwv[j*4], lwv[j*4+1]

    float acc0 = 0.f, acc1 = 0.f;

#pragma unroll
    for (int dir = 0; dir < 2; ++dir) {
        const int seg = (dir == 0) ? n : N + n;
        const int beg = off[seg], end = off[seg + 1];
        const int len = end - beg;
        if (len == 0) continue;
        const float* __restrict__ p0 = (dir == 0) ? pA0 : pB0;
        const float* __restrict__ p1 = (dir == 0) ? pA1 : pB1;
        float4 r1 = ((const float4*)p1)[n];

        if (len <= 64) {
            int sid = 0;
            float e0 = -INFINITY, e1 = -INFINITY, e2 = -INFINITY, e3 = -INFINITY;
            if (lane < len) {
                sid = csr[beg + lane];
                float4 r0 = ((const float4*)p0)[sid];
                e0 = lrelu(r0.x + r1.x);
                e1 = lrelu(r0.y + r1.y);
                e2 = lrelu(r0.z + r1.z);
                e3 = lrelu(r0.w + r1.w);
            }
            float m0 = e0, m1 = e1, m2 = e2, m3 = e3;
            if (len <= 16)      rmax4<16>(m0, m1, m2, m3);
            else if (len <= 32) rmax4<32>(m0, m1, m2, m3);
            else                rmax4<64>(m0, m1, m2, m3);
            float w0 = 0.f, w1 = 0.f, w2 = 0.f, w3 = 0.f;
            if (lane < len) {
                w0 = expf(e0 - m0); w1 = expf(e1 - m1);
                w2 = expf(e2 - m2); w3 = expf(e3 - m3);
            }
            float s0 = w0, s1 = w1, s2 = w2, s3 = w3;
            if (len <= 16)      rsum4<16>(s0, s1, s2, s3);
            else if (len <= 32) rsum4<32>(s0, s1, s2, s3);
            else                rsum4<64>(s0, s1, s2, s3);
            w0 *= 1.f / (s0 + EPS_SM);
            w1 *= 1.f / (s1 + EPS_SM);
            w2 *= 1.f / (s2 + EPS_SM);
            w3 *= 1.f / (s3 + EPS_SM);
            *(float4*)lwme = make_float4(w0, w2, w1, w3);
#pragma unroll 4
            for (int j = 0; j < len; ++j) {
                int sj = __builtin_amdgcn_readlane(sid, j);
                unsigned pk = hp_pk[((size_t)(unsigned)sj << 6) + lane];
                float wa = lwv[j * 4], wb = lwv[j * 4 + 1];
                acc0 += wa * __uint_as_float(pk << 16);
                acc1 += wb * __uint_as_float(pk & 0xffff0000u);
            }
        } else {
            // rare: deg > 64 — 2 reduction passes, then chunked LDS + readlane
            float m0 = -INFINITY, m1 = -INFINITY, m2 = -INFINITY, m3 = -INFINITY;
            for (int base = beg; base < end; base += 64) {
                int j = base + lane;
                if (j < end) {
                    int sid = csr[j];
                    float4 r0 = ((const float4*)p0)[sid];
                    m0 = fmaxf(m0, lrelu(r0.x + r1.x));
                    m1 = fmaxf(m1, lrelu(r0.y + r1.y));
                    m2 = fmaxf(m2, lrelu(r0.z + r1.z));
                    m3 = fmaxf(m3, lrelu(r0.w + r1.w));
                }
            }
            rmax4<64>(m0, m1, m2, m3);
            float s0 = 0.f, s1 = 0.f, s2 = 0.f, s3 = 0.f;
            for (int base = beg; base < end; base += 64) {
                int j = base + lane;
                if (j < end) {
                    int sid = csr[j];
                    float4 r0 = ((const float4*)p0)[sid];
                    s0 += expf(lrelu(r0.x + r1.x) - m0);
                    s1 += expf(lrelu(r0.y + r1.y) - m1);
                    s2 += expf(lrelu(r0.z + r1.z) - m2);
                    s3 += expf(lrelu(r0.w + r1.w) - m3);
                }
            }
            rsum4<64>(s0, s1, s2, s3);
            const float is0 = 1.f / (s0 + EPS_SM);
            const float is1 = 1.f / (s1 + EPS_SM);
            const float is2 = 1.f / (s2 + EPS_SM);
            const float is3 = 1.f / (s3 + EPS_SM);
            for (int base = beg; base < end; base += 64) {
                int cnt = min(64, end - base);
                int sid = 0;
                float w0 = 0.f, w1 = 0.f, w2 = 0.f, w3 = 0.f;
                if (lane < cnt) {
                    sid = csr[base + lane];
                    float4 r0 = ((const float4*)p0)[sid];
                    w0 = expf(lrelu(r0.x + r1.x) - m0) * is0;
                    w1 = expf(lrelu(r0.y + r1.y) - m1) * is1;
                    w2 = expf(lrelu(r0.z + r1.z) - m2) * is2;
                    w3 = expf(lrelu(r0.w + r1.w) - m3) * is3;
                }
                *(float4*)lwme = make_float4(w0, w2, w1, w3);
#pragma unroll 4
                for (int j = 0; j < cnt; ++j) {
                    int sj = __builtin_amdgcn_readlane(sid, j);
                    unsigned pk = hp_pk[((size_t)(unsigned)sj << 6) + lane];
                    float wa = lwv[j * 4], wb = lwv[j * 4 + 1];
                    acc0 += wa * __uint_as_float(pk << 16);
                    acc1 += wb * __uint_as_float(pk & 0xffff0000u);
                }
            }
        }
    }

    size_t bb = (size_t)n * DIM;
    float x0 = h_self[bb + lane] + acc0 + bias[lane];
    float x1 = h_self[bb + lane + 64] + acc1 + bias[lane + 64];
    float sum = x0 + x1, sq = x0 * x0 + x1 * x1;
#pragma unroll
    for (int m = 1; m < 64; m <<= 1) {
        sum += __shfl_xor(sum, m, 64);
        sq += __shfl_xor(sq, m, 64);
    }
    float mean = sum * (1.f / 128.f);
    float var = sq * (1.f / 128.f) - mean * mean;
    float inv = rsqrtf(var + EPS_LN);
    out[bb + lane] = (x0 - mean) * inv * gamma[lane] + beta[lane];
    out[bb + lane + 64] = (x1 - mean) * inv * gamma[lane + 64] + beta[lane + 64];
}

extern "C" void kernel_launch(void* const* d_in, const int* in_sizes, int n_in,
                              void* d_out, int out_size, void* d_ws, size_t ws_size,
                              hipStream_t stream) {
    const float* h      = (const float*)d_in[0];
    const int*   ei     = (const int*)d_in[1];
    const float* W      = (const float*)d_in[2];
    const float* W_self = (const float*)d_in[3];
    const float* a_in   = (const float*)d_in[4];
    const float* a_out  = (const float*)d_in[5];
    const float* bias   = (const float*)d_in[6];
    const float* gamma  = (const float*)d_in[7];
    const float* beta   = (const float*)d_in[8];
    float* out = (float*)d_out;

    const int N = in_sizes[0] / DIM;
    const int E = in_sizes[1] / 2;
    const int M = 2 * N;
    const int NBIN = (M + (1 << SH1) - 1) >> SH1;
    const int twoE = 2 * E;

    // workspace layout
    float* ws = (float*)d_ws;
    size_t off_f = 0;
    float* h_self = ws + off_f; off_f += (size_t)N * DIM;
    unsigned* hp_pk = (unsigned*)(ws + off_f); off_f += (size_t)N * 64;
    float* pA0 = ws + off_f; off_f += (size_t)N * 4;
    float* pA1 = ws + off_f; off_f += (size_t)N * 4;
    float* pB0 = ws + off_f; off_f += (size_t)N * 4;
    float* pB1 = ws + off_f; off_f += (size_t)N * 4;
    int* ip = (int*)(ws + off_f);
    size_t off_i = 0;
    int* bcnt  = ip + off_i; off_i += NBIN;
    int* bbase = ip + off_i; off_i += (size_t)NBIN + 1;
    int* bcur  = ip + off_i; off_i += NBIN;
    int* off   = ip + off_i; off_i += (size_t)M + 1;
    unsigned* rec = (unsigned*)(ip + off_i); off_i += (size_t)twoE;
    int* csr   = ip + off_i; off_i += (size_t)twoE;

    // ---- two-level CSR build ----
    hipMemsetAsync(bcnt, 0, (size_t)NBIN * sizeof(int), stream);
    bcnt1_k<<<256, 256, 0, stream>>>(ei, bcnt, E, N, NBIN);
    bscan1_k<<<1, 256, 0, stream>>>(bcnt, bbase, bcur, NBIN, twoE);
    part1_k<<<PB, 256, 0, stream>>>(ei, bcur, rec, E, N);
    build2_k<<<NBIN, 256, 0, stream>>>(rec, bbase, off, csr, M, twoE, NBIN);

    // ---- fused projections + dots + pack ----
    dual_gemm_k<<<(N + GROWS - 1) / GROWS, 256, 0, stream>>>(h, W, W_self, a_in, a_out,
                                                             h_self, hp_pk, pA0, pA1, pB0, pB1, N);

    // ---- fused aggregate + LN ----
    node_aggr_ln_k<<<(N + 3) / 4, 256, 0, stream>>>(hp_pk, h_self, pA0, pA1, pB0, pB1,
                                                    off, csr, bias, gamma, beta, out, N);
}

// Round 8
// 463.420 us; speedup vs baseline: 2.6579x; 1.1551x over previous
//
#include <hip/hip_runtime.h>
#include <math.h>

#define HEADS 4
#define HD 32
#define DIM 128
#define NEG_SLOPE 0.2f
#define EPS_SM 1e-8f
#define EPS_LN 1e-5f
#define GROWS 64
#define SH1 9              // 512 segments per coarse bin; NBIN = ceil(2N/512) <= 512
#define PB 128             // partition blocks (reservation chain depth)

__device__ __forceinline__ float lrelu(float x) { return x > 0.f ? x : NEG_SLOPE * x; }
__device__ __forceinline__ unsigned bf16rne(float x) {
    unsigned b = __float_as_uint(x);
    return (b + 0x7fffu + ((b >> 16) & 1u)) >> 16;
}

template<int LIM> __device__ __forceinline__ void rmax4(float& a, float& b, float& c, float& d) {
#pragma unroll
    for (int s = 1; s < LIM; s <<= 1) {
        a = fmaxf(a, __shfl_xor(a, s, 64));
        b = fmaxf(b, __shfl_xor(b, s, 64));
        c = fmaxf(c, __shfl_xor(c, s, 64));
        d = fmaxf(d, __shfl_xor(d, s, 64));
    }
}
template<int LIM> __device__ __forceinline__ void rsum4(float& a, float& b, float& c, float& d) {
#pragma unroll
    for (int s = 1; s < LIM; s <<= 1) {
        a += __shfl_xor(a, s, 64);
        b += __shfl_xor(b, s, 64);
        c += __shfl_xor(c, s, 64);
        d += __shfl_xor(d, s, 64);
    }
}

// ---------------- fused dual GEMM + attention dots + bf16 pack ----------------
__global__ __launch_bounds__(256) void dual_gemm_k(const float* __restrict__ h,
                                                   const float* __restrict__ W,
                                                   const float* __restrict__ V,
                                                   const float* __restrict__ a_in,
                                                   const float* __restrict__ a_out,
                                                   float* __restrict__ h_self,
                                                   unsigned* __restrict__ hp_pk,
                                                   float* __restrict__ pA0, float* __restrict__ pA1,
                                                   float* __restrict__ pB0, float* __restrict__ pB1,
                                                   int N) {
    __shared__ float As[32][GROWS];
    __shared__ float Ws[32][DIM];
    __shared__ float Vs[32][DIM];
    __shared__ float ainL[256], aoutL[256];
    const int tid = threadIdx.x;
    const int cg = tid & 15;
    const int rg = tid >> 4;
    const int row0 = blockIdx.x * GROWS;

    ainL[tid] = a_in[tid];
    aoutL[tid] = a_out[tid];

    float accP[4][8], accS[4][8];
#pragma unroll
    for (int r = 0; r < 4; ++r)
#pragma unroll
        for (int c = 0; c < 8; ++c) { accP[r][c] = 0.f; accS[r][c] = 0.f; }

    for (int kc = 0; kc < 4; ++kc) {
        __syncthreads();
#pragma unroll
        for (int p = 0; p < 2; ++p) {
            int f = tid + p * 256;
            int r = f >> 3, c4 = f & 7;
            float4 v = make_float4(0.f, 0.f, 0.f, 0.f);
            if (row0 + r < N) v = ((const float4*)h)[(size_t)(row0 + r) * 32 + kc * 8 + c4];
            As[c4 * 4 + 0][r] = v.x;
            As[c4 * 4 + 1][r] = v.y;
            As[c4 * 4 + 2][r] = v.z;
            As[c4 * 4 + 3][r] = v.w;
        }
#pragma unroll
        for (int p = 0; p < 4; ++p) {
            int f = tid + p * 256;
            int lk = f >> 5, c4 = f & 31;
            ((float4*)&Ws[lk][0])[c4] = ((const float4*)W)[(size_t)(kc * 32 + lk) * 32 + c4];
            ((float4*)&Vs[lk][0])[c4] = ((const float4*)V)[(size_t)(kc * 32 + lk) * 32 + c4];
        }
        __syncthreads();
#pragma unroll
        for (int kk = 0; kk < 32; ++kk) {
            float4 a = *(const float4*)&As[kk][rg * 4];
            float4 w0 = *(const float4*)&Ws[kk][cg * 8];
            float4 w1 = *(const float4*)&Ws[kk][cg * 8 + 4];
            float4 v0 = *(const float4*)&Vs[kk][cg * 8];
            float4 v1 = *(const float4*)&Vs[kk][cg * 8 + 4];
            float av[4] = {a.x, a.y, a.z, a.w};
            float wv[8] = {w0.x, w0.y, w0.z, w0.w, w1.x, w1.y, w1.z, w1.w};
            float vv[8] = {v0.x, v0.y, v0.z, v0.w, v1.x, v1.y, v1.z, v1.w};
#pragma unroll
            for (int r = 0; r < 4; ++r)
#pragma unroll
                for (int c = 0; c < 8; ++c) {
                    accP[r][c] += av[r] * wv[c];
                    accS[r][c] += av[r] * vv[c];
                }
        }
    }

    // ---- epilogue 1: h_self (f32) ----
#pragma unroll
    for (int r = 0; r < 4; ++r) {
        int row = row0 + rg * 4 + r;
        if (row < N) {
            float4 s0 = make_float4(accS[r][0], accS[r][1], accS[r][2], accS[r][3]);
            float4 s1 = make_float4(accS[r][4], accS[r][5], accS[r][6], accS[r][7]);
            ((float4*)h_self)[(size_t)row * 32 + cg * 2] = s0;
            ((float4*)h_self)[(size_t)row * 32 + cg * 2 + 1] = s1;
        }
    }

    // ---- epilogue 2: attention dot tables ----
    const int head = cg >> 2, qi = cg & 3;
#pragma unroll
    for (int r = 0; r < 4; ++r) {
        float d0 = 0.f, d1 = 0.f, d2 = 0.f, d3 = 0.f;
#pragma unroll
        for (int c = 0; c < 8; ++c) {
            float v = accP[r][c];
            int k = head * 64 + qi * 8 + c;
            d0 += v * ainL[k];
            d1 += v * ainL[k + 32];
            d2 += v * aoutL[k];
            d3 += v * aoutL[k + 32];
        }
        d0 += __shfl_xor(d0, 1, 64); d0 += __shfl_xor(d0, 2, 64);
        d1 += __shfl_xor(d1, 1, 64); d1 += __shfl_xor(d1, 2, 64);
        d2 += __shfl_xor(d2, 1, 64); d2 += __shfl_xor(d2, 2, 64);
        d3 += __shfl_xor(d3, 1, 64); d3 += __shfl_xor(d3, 2, 64);
        if (qi == 0) {
            int row = row0 + rg * 4 + r;
            if (row < N) {
                pA0[row * 4 + head] = d0;
                pA1[row * 4 + head] = d1;
                pB0[row * 4 + head] = d2;
                pB1[row * 4 + head] = d3;
            }
        }
    }

    // ---- epilogue 3: bf16 pack (c, c+64) via LDS half-exchange ----
    __syncthreads();
    float* lds2 = &Ws[0][0];
    if (cg >= 8) {
#pragma unroll
        for (int r = 0; r < 4; ++r) {
            int rl = rg * 4 + r;
#pragma unroll
            for (int c = 0; c < 8; ++c) lds2[rl * 64 + (cg - 8) * 8 + c] = accP[r][c];
        }
    }
    __syncthreads();
    if (cg < 8) {
#pragma unroll
        for (int r = 0; r < 4; ++r) {
            int rl = rg * 4 + r;
            int row = row0 + rl;
            if (row < N) {
                unsigned pks[8];
#pragma unroll
                for (int c = 0; c < 8; ++c)
                    pks[c] = bf16rne(accP[r][c]) | (bf16rne(lds2[rl * 64 + cg * 8 + c]) << 16);
                uint4* dst = (uint4*)(hp_pk + (size_t)row * 64 + cg * 8);
                dst[0] = make_uint4(pks[0], pks[1], pks[2], pks[3]);
                dst[1] = make_uint4(pks[4], pks[5], pks[6], pks[7]);
            }
        }
    }
}

// ---------------- two-level CSR build ----------------
__global__ __launch_bounds__(256) void bcnt1_k(const int* __restrict__ ei, int* __restrict__ bcnt,
                                               int E, int N, int NBIN) {
    __shared__ int lh[512];
    const int t = threadIdx.x;
    for (int i = t; i < 512; i += 256) lh[i] = 0;
    __syncthreads();
    for (int e = blockIdx.x * 256 + t; e < E; e += gridDim.x * 256) {
        int s = ei[e], d = ei[E + e];
        atomicAdd(&lh[d >> SH1], 1);
        atomicAdd(&lh[(N + s) >> SH1], 1);
    }
    __syncthreads();
    for (int i = t; i < NBIN; i += 256) {
        int v = lh[i];
        if (v) atomicAdd(&bcnt[i], v);
    }
}

__global__ __launch_bounds__(256) void bscan1_k(const int* __restrict__ bcnt,
                                                int* __restrict__ bbase, int* __restrict__ bcur,
                                                int NBIN, int twoE) {
    __shared__ int ls[256];
    int t = threadIdx.x;
    int i0 = 2 * t, i1 = 2 * t + 1;
    int v0 = (i0 < NBIN) ? bcnt[i0] : 0;
    int v1 = (i1 < NBIN) ? bcnt[i1] : 0;
    int pair = v0 + v1;
    ls[t] = pair;
    __syncthreads();
#pragma unroll
    for (int d = 1; d < 256; d <<= 1) {
        int u = (t >= d) ? ls[t - d] : 0;
        __syncthreads();
        ls[t] += u;
        __syncthreads();
    }
    int excl = ls[t] - pair;
    if (i0 < NBIN) { bbase[i0] = excl; bcur[i0] = excl; }
    if (i1 < NBIN) { bbase[i1] = excl + v0; bcur[i1] = excl + v0; }
    if (t == 0) bbase[NBIN] = twoE;
}

__global__ __launch_bounds__(256) void part1_k(const int* __restrict__ ei, int* __restrict__ bcur,
                                               unsigned* __restrict__ rec, int E, int N) {
    __shared__ int lcnt[512];
    __shared__ int gbase[512];
    const int t = threadIdx.x;
    const int CH = (E + gridDim.x - 1) / gridDim.x;
    const int e0 = blockIdx.x * CH;
    const int e1 = min(e0 + CH, E);
    for (int i = t; i < 512; i += 256) lcnt[i] = 0;
    __syncthreads();
    for (int e = e0 + t; e < e1; e += 256) {
        int s = ei[e], d = ei[E + e];
        atomicAdd(&lcnt[d >> SH1], 1);
        atomicAdd(&lcnt[(N + s) >> SH1], 1);
    }
    __syncthreads();
    for (int i = t; i < 512; i += 256) {
        int c = lcnt[i];
        gbase[i] = (c > 0) ? atomicAdd(&bcur[i], c) : 0;
        lcnt[i] = 0;
    }
    __syncthreads();
    for (int e = e0 + t; e < e1; e += 256) {
        int s = ei[e], d = ei[E + e];
        int b1 = d >> SH1;
        int r1 = atomicAdd(&lcnt[b1], 1);
        rec[gbase[b1] + r1] = (unsigned)s | ((unsigned)(d & 511) << 20);
        int so = N + s;
        int b2 = so >> SH1;
        int r2 = atomicAdd(&lcnt[b2], 1);
        rec[gbase[b2] + r2] = (unsigned)d | ((unsigned)(so & 511) << 20);
    }
}

__global__ __launch_bounds__(256) void build2_k(const unsigned* __restrict__ rec,
                                                const int* __restrict__ bbase,
                                                int* __restrict__ off, int* __restrict__ csr,
                                                int M, int twoE, int NBIN) {
    __shared__ int lcnt[512];
    __shared__ int lcur[512];
    __shared__ int ls[256];
    const int b = blockIdx.x;
    const int t = threadIdx.x;
    const int base = bbase[b];
    const int cnt = bbase[b + 1] - base;
    const int seg0 = b << SH1;
    for (int i = t; i < 512; i += 256) lcnt[i] = 0;
    __syncthreads();
    for (int k = t; k < cnt; k += 256) atomicAdd(&lcnt[rec[base + k] >> 20], 1);
    __syncthreads();
    int v0 = lcnt[2 * t], v1 = lcnt[2 * t + 1];
    int pair = v0 + v1;
    ls[t] = pair;
    __syncthreads();
#pragma unroll
    for (int d = 1; d < 256; d <<= 1) {
        int u = (t >= d) ? ls[t - d] : 0;
        __syncthreads();
        ls[t] += u;
        __syncthreads();
    }
    int excl = ls[t] - pair;
    lcur[2 * t] = excl;
    lcur[2 * t + 1] = excl + v0;
    int sg = seg0 + 2 * t;
    if (sg < M) off[sg] = base + excl;
    if (sg + 1 < M) off[sg + 1] = base + excl + v0;
    if (b == NBIN - 1 && t == 0) off[M] = twoE;
    __syncthreads();
    for (int k = t; k < cnt; k += 256) {
        unsigned r = rec[base + k];
        int pos = atomicAdd(&lcur[r >> 20], 1);
        csr[base + pos] = (int)(r & 0xFFFFFu);
    }
}

// ---------------- fused: per-node softmax-aggregate (both dirs) + combine + LN ----------------
// j-loop processes 2 edges/iter via half-waves: 32 lanes x dwordx2 covers one 64-dword row.
__global__ __launch_bounds__(256) void node_aggr_ln_k(const unsigned* __restrict__ hp_pk,
                                                      const float* __restrict__ h_self,
                                                      const float* __restrict__ pA0, const float* __restrict__ pA1,
                                                      const float* __restrict__ pB0, const float* __restrict__ pB1,
                                                      const int* __restrict__ off, const int* __restrict__ csr,
                                                      const float* __restrict__ bias,
                                                      const float* __restrict__ gamma,
                                                      const float* __restrict__ beta,
                                                      float* __restrict__ out, int N) {
    __shared__ uint4 lw[4][64];   // entry j: {pkA(w0,w2), sid, pkB(w1,w3), sid}
    const int wave = threadIdx.x >> 6;
    const int lane = threadIdx.x & 63;
    const int n = blockIdx.x * 4 + wave;
    if (n >= N) return;
    const int l31 = lane & 31;
    // byte offset within a 32B entry-pair: entry (lane>>5), sub-entry (l31>>4)
    const unsigned lwoff = (unsigned)(((lane >> 5) << 4) + ((l31 >> 4) << 3));
    const char* lwbase = (const char*)&lw[wave][0];
    const uint2* __restrict__ hpp2 = (const uint2*)hp_pk;   // row stride 32 uint2

    float a00 = 0.f, a01 = 0.f, a10 = 0.f, a11 = 0.f;

#pragma unroll
    for (int dir = 0; dir < 2; ++dir) {
        const int seg = (dir == 0) ? n : N + n;
        const int beg = off[seg], end = off[seg + 1];
        const int len = end - beg;
        if (len == 0) continue;
        const float* __restrict__ p0 = (dir == 0) ? pA0 : pB0;
        const float* __restrict__ p1 = (dir == 0) ? pA1 : pB1;
        float4 r1 = ((const float4*)p1)[n];

        if (len <= 64) {
            int sid = 0;
            float e0 = -INFINITY, e1 = -INFINITY, e2 = -INFINITY, e3 = -INFINITY;
            if (lane < len) {
                sid = csr[beg + lane];
                float4 r0 = ((const float4*)p0)[sid];
                e0 = lrelu(r0.x + r1.x);
                e1 = lrelu(r0.y + r1.y);
                e2 = lrelu(r0.z + r1.z);
                e3 = lrelu(r0.w + r1.w);
            }
            float m0 = e0, m1 = e1, m2 = e2, m3 = e3;
            if (len <= 16)      rmax4<16>(m0, m1, m2, m3);
            else if (len <= 32) rmax4<32>(m0, m1, m2, m3);
            else                rmax4<64>(m0, m1, m2, m3);
            float w0 = 0.f, w1 = 0.f, w2 = 0.f, w3 = 0.f;
            if (lane < len) {
                w0 = expf(e0 - m0); w1 = expf(e1 - m1);
                w2 = expf(e2 - m2); w3 = expf(e3 - m3);
            }
            float s0 = w0, s1 = w1, s2 = w2, s3 = w3;
            if (len <= 16)      rsum4<16>(s0, s1, s2, s3);
            else if (len <= 32) rsum4<32>(s0, s1, s2, s3);
            else                rsum4<64>(s0, s1, s2, s3);
            w0 *= 1.f / (s0 + EPS_SM);
            w1 *= 1.f / (s1 + EPS_SM);
            w2 *= 1.f / (s2 + EPS_SM);
            w3 *= 1.f / (s3 + EPS_SM);
            unsigned pkA = bf16rne(w0) | (bf16rne(w2) << 16);
            unsigned pkB = bf16rne(w1) | (bf16rne(w3) << 16);
            lw[wave][lane] = make_uint4(pkA, (unsigned)sid, pkB, (unsigned)sid);
            const int nt = (len + 1) >> 1;
#pragma unroll 2
            for (int t = 0; t < nt; ++t) {
                uint2 wv = *(const uint2*)(lwbase + t * 32 + lwoff);
                uint2 v = hpp2[((size_t)wv.y << 5) + l31];
                float wa = __uint_as_float(wv.x << 16);
                float wb = __uint_as_float(wv.x & 0xffff0000u);
                a00 += wa * __uint_as_float(v.x << 16);
                a10 += wb * __uint_as_float(v.x & 0xffff0000u);
                a01 += wa * __uint_as_float(v.y << 16);
                a11 += wb * __uint_as_float(v.y & 0xffff0000u);
            }
        } else {
            // rare: deg > 64 — 2 reduction passes, then chunked
            float m0 = -INFINITY, m1 = -INFINITY, m2 = -INFINITY, m3 = -INFINITY;
            for (int base = beg; base < end; base += 64) {
                int j = base + lane;
                if (j < end) {
                    int sid = csr[j];
                    float4 r0 = ((const float4*)p0)[sid];
                    m0 = fmaxf(m0, lrelu(r0.x + r1.x));
                    m1 = fmaxf(m1, lrelu(r0.y + r1.y));
                    m2 = fmaxf(m2, lrelu(r0.z + r1.z));
                    m3 = fmaxf(m3, lrelu(r0.w + r1.w));
                }
            }
            rmax4<64>(m0, m1, m2, m3);
            float s0 = 0.f, s1 = 0.f, s2 = 0.f, s3 = 0.f;
            for (int base = beg; base < end; base += 64) {
                int j = base + lane;
                if (j < end) {
                    int sid = csr[j];
                    float4 r0 = ((const float4*)p0)[sid];
                    s0 += expf(lrelu(r0.x + r1.x) - m0);
                    s1 += expf(lrelu(r0.y + r1.y) - m1);
                    s2 += expf(lrelu(r0.z + r1.z) - m2);
                    s3 += expf(lrelu(r0.w + r1.w) - m3);
                }
            }
            rsum4<64>(s0, s1, s2, s3);
            const float is0 = 1.f / (s0 + EPS_SM);
            const float is1 = 1.f / (s1 + EPS_SM);
            const float is2 = 1.f / (s2 + EPS_SM);
            const float is3 = 1.f / (s3 + EPS_SM);
            for (int base = beg; base < end; base += 64) {
                int cnt = min(64, end - base);
                int sid = 0;
                float w0 = 0.f, w1 = 0.f, w2 = 0.f, w3 = 0.f;
                if (lane < cnt) {
                    sid = csr[base + lane];
                    float4 r0 = ((const float4*)p0)[sid];
                    w0 = expf(lrelu(r0.x + r1.x) - m0) * is0;
                    w1 = expf(lrelu(r0.y + r1.y) - m1) * is1;
                    w2 = expf(lrelu(r0.z + r1.z) - m2) * is2;
                    w3 = expf(lrelu(r0.w + r1.w) - m3) * is3;
                }
                unsigned pkA = bf16rne(w0) | (bf16rne(w2) << 16);
                unsigned pkB = bf16rne(w1) | (bf16rne(w3) << 16);
                lw[wave][lane] = make_uint4(pkA, (unsigned)sid, pkB, (unsigned)sid);
                const int nt = (cnt + 1) >> 1;
#pragma unroll 2
                for (int t = 0; t < nt; ++t) {
                    uint2 wv = *(const uint2*)(lwbase + t * 32 + lwoff);
                    uint2 v = hpp2[((size_t)wv.y << 5) + l31];
                    float wa = __uint_as_float(wv.x << 16);
                    float wb = __uint_as_float(wv.x & 0xffff0000u);
                    a00 += wa * __uint_as_float(v.x << 16);
                    a10 += wb * __uint_as_float(v.x & 0xffff0000u);
                    a01 += wa * __uint_as_float(v.y << 16);
                    a11 += wb * __uint_as_float(v.y & 0xffff0000u);
                }
            }
        }
    }

    // merge the two half-wave partial sums (each half covered a disjoint edge subset)
    a00 += __shfl_xor(a00, 32, 64);
    a01 += __shfl_xor(a01, 32, 64);
    a10 += __shfl_xor(a10, 32, 64);
    a11 += __shfl_xor(a11, 32, 64);

    // combine + LayerNorm (lane holds channels 2*l31, 2*l31+1, +64, +65; duplicated across halves)
    size_t bb = (size_t)n * DIM;
    float2 hs0 = *(const float2*)(h_self + bb + 2 * l31);
    float2 hs1 = *(const float2*)(h_self + bb + 64 + 2 * l31);
    float2 b0 = *(const float2*)(bias + 2 * l31);
    float2 b1 = *(const float2*)(bias + 64 + 2 * l31);
    float x00 = hs0.x + a00 + b0.x;
    float x01 = hs0.y + a01 + b0.y;
    float x10 = hs1.x + a10 + b1.x;
    float x11 = hs1.y + a11 + b1.y;
    float sum = x00 + x01 + x10 + x11;
    float sq = x00 * x00 + x01 * x01 + x10 * x10 + x11 * x11;
#pragma unroll
    for (int m = 1; m < 64; m <<= 1) {
        sum += __shfl_xor(sum, m, 64);
        sq += __shfl_xor(sq, m, 64);
    }
    float mean = sum * (1.f / 256.f);          // each channel counted twice
    float var = sq * (1.f / 256.f) - mean * mean;
    float inv = rsqrtf(var + EPS_LN);
    if (lane < 32) {
        float2 g0 = *(const float2*)(gamma + 2 * l31);
        float2 g1 = *(const float2*)(gamma + 64 + 2 * l31);
        float2 be0 = *(const float2*)(beta + 2 * l31);
        float2 be1 = *(const float2*)(beta + 64 + 2 * l31);
        float2 y0 = make_float2((x00 - mean) * inv * g0.x + be0.x,
                                (x01 - mean) * inv * g0.y + be0.y);
        float2 y1 = make_float2((x10 - mean) * inv * g1.x + be1.x,
                                (x11 - mean) * inv * g1.y + be1.y);
        *(float2*)(out + bb + 2 * l31) = y0;
        *(float2*)(out + bb + 64 + 2 * l31) = y1;
    }
}

extern "C" void kernel_launch(void* const* d_in, const int* in_sizes, int n_in,
                              void* d_out, int out_size, void* d_ws, size_t ws_size,
                              hipStream_t stream) {
    const float* h      = (const float*)d_in[0];
    const int*   ei     = (const int*)d_in[1];
    const float* W      = (const float*)d_in[2];
    const float* W_self = (const float*)d_in[3];
    const float* a_in   = (const float*)d_in[4];
    const float* a_out  = (const float*)d_in[5];
    const float* bias   = (const float*)d_in[6];
    const float* gamma  = (const float*)d_in[7];
    const float* beta   = (const float*)d_in[8];
    float* out = (float*)d_out;

    const int N = in_sizes[0] / DIM;
    const int E = in_sizes[1] / 2;
    const int M = 2 * N;
    const int NBIN = (M + (1 << SH1) - 1) >> SH1;
    const int twoE = 2 * E;

    // workspace layout
    float* ws = (float*)d_ws;
    size_t off_f = 0;
    float* h_self = ws + off_f; off_f += (size_t)N * DIM;
    unsigned* hp_pk = (unsigned*)(ws + off_f); off_f += (size_t)N * 64;
    float* pA0 = ws + off_f; off_f += (size_t)N * 4;
    float* pA1 = ws + off_f; off_f += (size_t)N * 4;
    float* pB0 = ws + off_f; off_f += (size_t)N * 4;
    float* pB1 = ws + off_f; off_f += (size_t)N * 4;
    int* ip = (int*)(ws + off_f);
    size_t off_i = 0;
    int* bcnt  = ip + off_i; off_i += NBIN;
    int* bbase = ip + off_i; off_i += (size_t)NBIN + 1;
    int* bcur  = ip + off_i; off_i += NBIN;
    int* off   = ip + off_i; off_i += (size_t)M + 1;
    unsigned* rec = (unsigned*)(ip + off_i); off_i += (size_t)twoE;
    int* csr   = ip + off_i; off_i += (size_t)twoE;

    // ---- two-level CSR build ----
    hipMemsetAsync(bcnt, 0, (size_t)NBIN * sizeof(int), stream);
    bcnt1_k<<<256, 256, 0, stream>>>(ei, bcnt, E, N, NBIN);
    bscan1_k<<<1, 256, 0, stream>>>(bcnt, bbase, bcur, NBIN, twoE);
    part1_k<<<PB, 256, 0, stream>>>(ei, bcur, rec, E, N);
    build2_k<<<NBIN, 256, 0, stream>>>(rec, bbase, off, csr, M, twoE, NBIN);

    // ---- fused projections + dots + pack ----
    dual_gemm_k<<<(N + GROWS - 1) / GROWS, 256, 0, stream>>>(h, W, W_self, a_in, a_out,
                                                             h_self, hp_pk, pA0, pA1, pB0, pB1, N);

    // ---- fused aggregate + LN ----
    node_aggr_ln_k<<<(N + 3) / 4, 256, 0, stream>>>(hp_pk, h_self, pA0, pA1, pB0, pB1,
                                                    off, csr, bias, gamma, beta, out, N);
}

// Round 9
// 454.275 us; speedup vs baseline: 2.7114x; 1.0201x over previous
//
#include <hip/hip_runtime.h>
#include <math.h>

#define HEADS 4
#define HD 32
#define DIM 128
#define NEG_SLOPE 0.2f
#define EPS_SM 1e-8f
#define EPS_LN 1e-5f
#define GROWS 64
#define SH1 9              // 512 segments per coarse bin; NBIN = ceil(2N/512) <= 512
#define PB 128             // partition blocks

__device__ __forceinline__ float lrelu(float x) { return x > 0.f ? x : NEG_SLOPE * x; }
__device__ __forceinline__ unsigned bf16rne(float x) {
    unsigned b = __float_as_uint(x);
    return (b + 0x7fffu + ((b >> 16) & 1u)) >> 16;
}

template<int LIM> __device__ __forceinline__ void rmax4(float& a, float& b, float& c, float& d) {
#pragma unroll
    for (int s = 1; s < LIM; s <<= 1) {
        a = fmaxf(a, __shfl_xor(a, s, 64));
        b = fmaxf(b, __shfl_xor(b, s, 64));
        c = fmaxf(c, __shfl_xor(c, s, 64));
        d = fmaxf(d, __shfl_xor(d, s, 64));
    }
}
template<int LIM> __device__ __forceinline__ void rsum4(float& a, float& b, float& c, float& d) {
#pragma unroll
    for (int s = 1; s < LIM; s <<= 1) {
        a += __shfl_xor(a, s, 64);
        b += __shfl_xor(b, s, 64);
        c += __shfl_xor(c, s, 64);
        d += __shfl_xor(d, s, 64);
    }
}

// ---------------- fused dual GEMM + attention dots + bf16 pack ----------------
__global__ __launch_bounds__(256) void dual_gemm_k(const float* __restrict__ h,
                                                   const float* __restrict__ W,
                                                   const float* __restrict__ V,
                                                   const float* __restrict__ a_in,
                                                   const float* __restrict__ a_out,
                                                   float* __restrict__ h_self,
                                                   unsigned* __restrict__ hp_pk,
                                                   float* __restrict__ pA0, float* __restrict__ pA1,
                                                   float* __restrict__ pB0, float* __restrict__ pB1,
                                                   int N) {
    __shared__ float As[32][GROWS];
    __shared__ float Ws[32][DIM];
    __shared__ float Vs[32][DIM];
    __shared__ float ainL[256], aoutL[256];
    const int tid = threadIdx.x;
    const int cg = tid & 15;
    const int rg = tid >> 4;
    const int row0 = blockIdx.x * GROWS;

    ainL[tid] = a_in[tid];
    aoutL[tid] = a_out[tid];

    float accP[4][8], accS[4][8];
#pragma unroll
    for (int r = 0; r < 4; ++r)
#pragma unroll
        for (int c = 0; c < 8; ++c) { accP[r][c] = 0.f; accS[r][c] = 0.f; }

    for (int kc = 0; kc < 4; ++kc) {
        __syncthreads();
#pragma unroll
        for (int p = 0; p < 2; ++p) {
            int f = tid + p * 256;
            int r = f >> 3, c4 = f & 7;
            float4 v = make_float4(0.f, 0.f, 0.f, 0.f);
            if (row0 + r < N) v = ((const float4*)h)[(size_t)(row0 + r) * 32 + kc * 8 + c4];
            As[c4 * 4 + 0][r] = v.x;
            As[c4 * 4 + 1][r] = v.y;
            As[c4 * 4 + 2][r] = v.z;
            As[c4 * 4 + 3][r] = v.w;
        }
#pragma unroll
        for (int p = 0; p < 4; ++p) {
            int f = tid + p * 256;
            int lk = f >> 5, c4 = f & 31;
            ((float4*)&Ws[lk][0])[c4] = ((const float4*)W)[(size_t)(kc * 32 + lk) * 32 + c4];
            ((float4*)&Vs[lk][0])[c4] = ((const float4*)V)[(size_t)(kc * 32 + lk) * 32 + c4];
        }
        __syncthreads();
#pragma unroll
        for (int kk = 0; kk < 32; ++kk) {
            float4 a = *(const float4*)&As[kk][rg * 4];
            float4 w0 = *(const float4*)&Ws[kk][cg * 8];
            float4 w1 = *(const float4*)&Ws[kk][cg * 8 + 4];
            float4 v0 = *(const float4*)&Vs[kk][cg * 8];
            float4 v1 = *(const float4*)&Vs[kk][cg * 8 + 4];
            float av[4] = {a.x, a.y, a.z, a.w};
            float wv[8] = {w0.x, w0.y, w0.z, w0.w, w1.x, w1.y, w1.z, w1.w};
            float vv[8] = {v0.x, v0.y, v0.z, v0.w, v1.x, v1.y, v1.z, v1.w};
#pragma unroll
            for (int r = 0; r < 4; ++r)
#pragma unroll
                for (int c = 0; c < 8; ++c) {
                    accP[r][c] += av[r] * wv[c];
                    accS[r][c] += av[r] * vv[c];
                }
        }
    }

    // ---- epilogue 1: h_self (f32) ----
#pragma unroll
    for (int r = 0; r < 4; ++r) {
        int row = row0 + rg * 4 + r;
        if (row < N) {
            float4 s0 = make_float4(accS[r][0], accS[r][1], accS[r][2], accS[r][3]);
            float4 s1 = make_float4(accS[r][4], accS[r][5], accS[r][6], accS[r][7]);
            ((float4*)h_self)[(size_t)row * 32 + cg * 2] = s0;
            ((float4*)h_self)[(size_t)row * 32 + cg * 2 + 1] = s1;
        }
    }

    // ---- epilogue 2: attention dot tables ----
    const int head = cg >> 2, qi = cg & 3;
#pragma unroll
    for (int r = 0; r < 4; ++r) {
        float d0 = 0.f, d1 = 0.f, d2 = 0.f, d3 = 0.f;
#pragma unroll
        for (int c = 0; c < 8; ++c) {
            float v = accP[r][c];
            int k = head * 64 + qi * 8 + c;
            d0 += v * ainL[k];
            d1 += v * ainL[k + 32];
            d2 += v * aoutL[k];
            d3 += v * aoutL[k + 32];
        }
        d0 += __shfl_xor(d0, 1, 64); d0 += __shfl_xor(d0, 2, 64);
        d1 += __shfl_xor(d1, 1, 64); d1 += __shfl_xor(d1, 2, 64);
        d2 += __shfl_xor(d2, 1, 64); d2 += __shfl_xor(d2, 2, 64);
        d3 += __shfl_xor(d3, 1, 64); d3 += __shfl_xor(d3, 2, 64);
        if (qi == 0) {
            int row = row0 + rg * 4 + r;
            if (row < N) {
                pA0[row * 4 + head] = d0;
                pA1[row * 4 + head] = d1;
                pB0[row * 4 + head] = d2;
                pB1[row * 4 + head] = d3;
            }
        }
    }

    // ---- epilogue 3: bf16 pack (c, c+64) via LDS half-exchange ----
    __syncthreads();
    float* lds2 = &Ws[0][0];
    if (cg >= 8) {
#pragma unroll
        for (int r = 0; r < 4; ++r) {
            int rl = rg * 4 + r;
#pragma unroll
            for (int c = 0; c < 8; ++c) lds2[rl * 64 + (cg - 8) * 8 + c] = accP[r][c];
        }
    }
    __syncthreads();
    if (cg < 8) {
#pragma unroll
        for (int r = 0; r < 4; ++r) {
            int rl = rg * 4 + r;
            int row = row0 + rl;
            if (row < N) {
                unsigned pks[8];
#pragma unroll
                for (int c = 0; c < 8; ++c)
                    pks[c] = bf16rne(accP[r][c]) | (bf16rne(lds2[rl * 64 + cg * 8 + c]) << 16);
                uint4* dst = (uint4*)(hp_pk + (size_t)row * 64 + cg * 8);
                dst[0] = make_uint4(pks[0], pks[1], pks[2], pks[3]);
                dst[1] = make_uint4(pks[4], pks[5], pks[6], pks[7]);
            }
        }
    }
}

// ---------------- deterministic two-level CSR build (no global atomics) ----------------
// part1a: per-block bin histogram -> cntmat[bin*PB + blk]
__global__ __launch_bounds__(256) void part1a_k(const int* __restrict__ ei, int* __restrict__ cntmat,
                                                int E, int N, int NBIN) {
    __shared__ int lcnt[512];
    const int t = threadIdx.x;
    const int CH = (E + gridDim.x - 1) / gridDim.x;
    const int e0 = blockIdx.x * CH;
    const int e1 = min(e0 + CH, E);
    for (int i = t; i < 512; i += 256) lcnt[i] = 0;
    __syncthreads();
    for (int e = e0 + t; e < e1; e += 256) {
        int s = ei[e], d = ei[E + e];
        atomicAdd(&lcnt[d >> SH1], 1);
        atomicAdd(&lcnt[(N + s) >> SH1], 1);
    }
    __syncthreads();
    for (int i = t; i < NBIN; i += 256) cntmat[i * PB + blockIdx.x] = lcnt[i];
}

// scanB: per-bin exclusive scan over the PB blocks -> blkoff, btot
__global__ __launch_bounds__(128) void scanB_k(const int* __restrict__ cntmat,
                                               int* __restrict__ blkoff, int* __restrict__ btot) {
    __shared__ int ls[PB];
    const int bin = blockIdx.x;
    const int t = threadIdx.x;
    int v = cntmat[bin * PB + t];
    ls[t] = v;
    __syncthreads();
#pragma unroll
    for (int d = 1; d < PB; d <<= 1) {
        int u = (t >= d) ? ls[t - d] : 0;
        __syncthreads();
        ls[t] += u;
        __syncthreads();
    }
    blkoff[bin * PB + t] = ls[t] - v;
    if (t == PB - 1) btot[bin] = ls[t];
}

// scanC: exclusive scan over NBIN bin totals -> bbase[NBIN+1]
__global__ __launch_bounds__(256) void scanC_k(const int* __restrict__ btot,
                                               int* __restrict__ bbase, int NBIN, int twoE) {
    __shared__ int ls[256];
    int t = threadIdx.x;
    int i0 = 2 * t, i1 = 2 * t + 1;
    int v0 = (i0 < NBIN) ? btot[i0] : 0;
    int v1 = (i1 < NBIN) ? btot[i1] : 0;
    int pair = v0 + v1;
    ls[t] = pair;
    __syncthreads();
#pragma unroll
    for (int d = 1; d < 256; d <<= 1) {
        int u = (t >= d) ? ls[t - d] : 0;
        __syncthreads();
        ls[t] += u;
        __syncthreads();
    }
    int excl = ls[t] - pair;
    if (i0 < NBIN) bbase[i0] = excl;
    if (i1 < NBIN) bbase[i1] = excl + v0;
    if (t == 0) bbase[NBIN] = twoE;
}

// part1b: scatter into reserved runs (deterministic bases, LDS-local ranks)
__global__ __launch_bounds__(256) void part1b_k(const int* __restrict__ ei,
                                                const int* __restrict__ bbase,
                                                const int* __restrict__ blkoff,
                                                unsigned* __restrict__ rec, int E, int N, int NBIN) {
    __shared__ int gb[512];
    __shared__ int lcur[512];
    const int t = threadIdx.x;
    const int CH = (E + gridDim.x - 1) / gridDim.x;
    const int e0 = blockIdx.x * CH;
    const int e1 = min(e0 + CH, E);
    for (int i = t; i < 512; i += 256) lcur[i] = 0;
    for (int i = t; i < NBIN; i += 256) gb[i] = bbase[i] + blkoff[i * PB + blockIdx.x];
    __syncthreads();
    for (int e = e0 + t; e < e1; e += 256) {
        int s = ei[e], d = ei[E + e];
        int b1 = d >> SH1;
        int r1 = atomicAdd(&lcur[b1], 1);
        rec[gb[b1] + r1] = (unsigned)s | ((unsigned)(d & 511) << 20);
        int so = N + s;
        int b2 = so >> SH1;
        int r2 = atomicAdd(&lcur[b2], 1);
        rec[gb[b2] + r2] = (unsigned)d | ((unsigned)(so & 511) << 20);
    }
}

__global__ __launch_bounds__(256) void build2_k(const unsigned* __restrict__ rec,
                                                const int* __restrict__ bbase,
                                                int* __restrict__ off, int* __restrict__ csr,
                                                int M, int twoE, int NBIN) {
    __shared__ int lcnt[512];
    __shared__ int lcur[512];
    __shared__ int ls[256];
    const int b = blockIdx.x;
    const int t = threadIdx.x;
    const int base = bbase[b];
    const int cnt = bbase[b + 1] - base;
    const int seg0 = b << SH1;
    for (int i = t; i < 512; i += 256) lcnt[i] = 0;
    __syncthreads();
    for (int k = t; k < cnt; k += 256) atomicAdd(&lcnt[rec[base + k] >> 20], 1);
    __syncthreads();
    int v0 = lcnt[2 * t], v1 = lcnt[2 * t + 1];
    int pair = v0 + v1;
    ls[t] = pair;
    __syncthreads();
#pragma unroll
    for (int d = 1; d < 256; d <<= 1) {
        int u = (t >= d) ? ls[t - d] : 0;
        __syncthreads();
        ls[t] += u;
        __syncthreads();
    }
    int excl = ls[t] - pair;
    lcur[2 * t] = excl;
    lcur[2 * t + 1] = excl + v0;
    int sg = seg0 + 2 * t;
    if (sg < M) off[sg] = base + excl;
    if (sg + 1 < M) off[sg + 1] = base + excl + v0;
    if (b == NBIN - 1 && t == 0) off[M] = twoE;
    __syncthreads();
    for (int k = t; k < cnt; k += 256) {
        unsigned r = rec[base + k];
        int pos = atomicAdd(&lcur[r >> 20], 1);
        csr[base + pos] = (int)(r & 0xFFFFFu);
    }
}

// ---------------- fused: per-node softmax-aggregate + combine + LN ----------------
// j-loop: 4 edges/iter via quarter-waves (16 lanes x dwordx4 = one 256B row).
__global__ __launch_bounds__(256) void node_aggr_ln_k(const unsigned* __restrict__ hp_pk,
                                                      const float* __restrict__ h_self,
                                                      const float* __restrict__ pA0, const float* __restrict__ pA1,
                                                      const float* __restrict__ pB0, const float* __restrict__ pB1,
                                                      const int* __restrict__ off, const int* __restrict__ csr,
                                                      const float* __restrict__ bias,
                                                      const float* __restrict__ gamma,
                                                      const float* __restrict__ beta,
                                                      float* __restrict__ out, int N) {
    __shared__ uint4 lw[4][64];   // entry j: {pkA(w0,w2), sid, pkB(w1,w3), sid}
    const int wave = threadIdx.x >> 6;
    const int lane = threadIdx.x & 63;
    const int n = blockIdx.x * 4 + wave;
    if (n >= N) return;
    const int l15 = lane & 15;
    const int q = lane >> 4;
    // lane reads 8B of entry (4t+q): pkA-half if l15<8 else pkB-half
    const unsigned lwoff = (unsigned)((q << 4) + ((l15 >> 3) << 3));
    const char* lwbase = (const char*)&lw[wave][0];
    const uint4* __restrict__ hpp4 = (const uint4*)hp_pk;   // row stride 16 uint4

    float alo0 = 0.f, alo1 = 0.f, alo2 = 0.f, alo3 = 0.f;
    float ahi0 = 0.f, ahi1 = 0.f, ahi2 = 0.f, ahi3 = 0.f;

#pragma unroll
    for (int dir = 0; dir < 2; ++dir) {
        const int seg = (dir == 0) ? n : N + n;
        const int beg = off[seg], end = off[seg + 1];
        const int len = end - beg;
        if (len == 0) continue;
        const float* __restrict__ p0 = (dir == 0) ? pA0 : pB0;
        const float* __restrict__ p1 = (dir == 0) ? pA1 : pB1;
        float4 r1 = ((const float4*)p1)[n];

        if (len <= 64) {
            int sid = 0;
            float e0 = -INFINITY, e1 = -INFINITY, e2 = -INFINITY, e3 = -INFINITY;
            if (lane < len) {
                sid = csr[beg + lane];
                float4 r0 = ((const float4*)p0)[sid];
                e0 = lrelu(r0.x + r1.x);
                e1 = lrelu(r0.y + r1.y);
                e2 = lrelu(r0.z + r1.z);
                e3 = lrelu(r0.w + r1.w);
            }
            float m0 = e0, m1 = e1, m2 = e2, m3 = e3;
            if (len <= 16)      rmax4<16>(m0, m1, m2, m3);
            else if (len <= 32) rmax4<32>(m0, m1, m2, m3);
            else                rmax4<64>(m0, m1, m2, m3);
            float w0 = 0.f, w1 = 0.f, w2 = 0.f, w3 = 0.f;
            if (lane < len) {
                w0 = expf(e0 - m0); w1 = expf(e1 - m1);
                w2 = expf(e2 - m2); w3 = expf(e3 - m3);
            }
            float s0 = w0, s1 = w1, s2 = w2, s3 = w3;
            if (len <= 16)      rsum4<16>(s0, s1, s2, s3);
            else if (len <= 32) rsum4<32>(s0, s1, s2, s3);
            else                rsum4<64>(s0, s1, s2, s3);
            w0 *= 1.f / (s0 + EPS_SM);
            w1 *= 1.f / (s1 + EPS_SM);
            w2 *= 1.f / (s2 + EPS_SM);
            w3 *= 1.f / (s3 + EPS_SM);
            unsigned pkA = bf16rne(w0) | (bf16rne(w2) << 16);
            unsigned pkB = bf16rne(w1) | (bf16rne(w3) << 16);
            lw[wave][lane] = make_uint4(pkA, (unsigned)sid, pkB, (unsigned)sid);
            const int nt = (len + 3) >> 2;
#pragma unroll 2
            for (int t = 0; t < nt; ++t) {
                uint2 wv = *(const uint2*)(lwbase + t * 64 + lwoff);
                uint4 v = hpp4[((size_t)wv.y << 4) + l15];
                float wa = __uint_as_float(wv.x << 16);
                float wb = __uint_as_float(wv.x & 0xffff0000u);
                alo0 += wa * __uint_as_float(v.x << 16);
                ahi0 += wb * __uint_as_float(v.x & 0xffff0000u);
                alo1 += wa * __uint_as_float(v.y << 16);
                ahi1 += wb * __uint_as_float(v.y & 0xffff0000u);
                alo2 += wa * __uint_as_float(v.z << 16);
                ahi2 += wb * __uint_as_float(v.z & 0xffff0000u);
                alo3 += wa * __uint_as_float(v.w << 16);
                ahi3 += wb * __uint_as_float(v.w & 0xffff0000u);
            }
        } else {
            // rare: deg > 64 — 2 reduction passes, then chunked
            float m0 = -INFINITY, m1 = -INFINITY, m2 = -INFINITY, m3 = -INFINITY;
            for (int base = beg; base < end; base += 64) {
                int j = base + lane;
                if (j < end) {
                    int sid = csr[j];
                    float4 r0 = ((const float4*)p0)[sid];
                    m0 = fmaxf(m0, lrelu(r0.x + r1.x));
                    m1 = fmaxf(m1, lrelu(r0.y + r1.y));
                    m2 = fmaxf(m2, lrelu(r0.z + r1.z));
                    m3 = fmaxf(m3, lrelu(r0.w + r1.w));
                }
            }
            rmax4<64>(m0, m1, m2, m3);
            float s0 = 0.f, s1 = 0.f, s2 = 0.f, s3 = 0.f;
            for (int base = beg; base < end; base += 64) {
                int j = base + lane;
                if (j < end) {
                    int sid = csr[j];
                    float4 r0 = ((const float4*)p0)[sid];
                    s0 += expf(lrelu(r0.x + r1.x) - m0);
                    s1 += expf(lrelu(r0.y + r1.y) - m1);
                    s2 += expf(lrelu(r0.z + r1.z) - m2);
                    s3 += expf(lrelu(r0.w + r1.w) - m3);
                }
            }
            rsum4<64>(s0, s1, s2, s3);
            const float is0 = 1.f / (s0 + EPS_SM);
            const float is1 = 1.f / (s1 + EPS_SM);
            const float is2 = 1.f / (s2 + EPS_SM);
            const float is3 = 1.f / (s3 + EPS_SM);
            for (int base = beg; base < end; base += 64) {
                int cnt = min(64, end - base);
                int sid = 0;
                float w0 = 0.f, w1 = 0.f, w2 = 0.f, w3 = 0.f;
                if (lane < cnt) {
                    sid = csr[base + lane];
                    float4 r0 = ((const float4*)p0)[sid];
                    w0 = expf(lrelu(r0.x + r1.x) - m0) * is0;
                    w1 = expf(lrelu(r0.y + r1.y) - m1) * is1;
                    w2 = expf(lrelu(r0.z + r1.z) - m2) * is2;
                    w3 = expf(lrelu(r0.w + r1.w) - m3) * is3;
                }
                unsigned pkA = bf16rne(w0) | (bf16rne(w2) << 16);
                unsigned pkB = bf16rne(w1) | (bf16rne(w3) << 16);
                lw[wave][lane] = make_uint4(pkA, (unsigned)sid, pkB, (unsigned)sid);
                const int nt = (cnt + 3) >> 2;
#pragma unroll 2
                for (int t = 0; t < nt; ++t) {
                    uint2 wv = *(const uint2*)(lwbase + t * 64 + lwoff);
                    uint4 v = hpp4[((size_t)wv.y << 4) + l15];
                    float wa = __uint_as_float(wv.x << 16);
                    float wb = __uint_as_float(wv.x & 0xffff0000u);
                    alo0 += wa * __uint_as_float(v.x << 16);
                    ahi0 += wb * __uint_as_float(v.x & 0xffff0000u);
                    alo1 += wa * __uint_as_float(v.y << 16);
                    ahi1 += wb * __uint_as_float(v.y & 0xffff0000u);
                    alo2 += wa * __uint_as_float(v.z << 16);
                    ahi2 += wb * __uint_as_float(v.z & 0xffff0000u);
                    alo3 += wa * __uint_as_float(v.w << 16);
                    ahi3 += wb * __uint_as_float(v.w & 0xffff0000u);
                }
            }
        }
    }

    // merge quarter-wave partials (each quarter covered a disjoint edge subset)
#pragma unroll
    for (int s = 16; s < 64; s <<= 1) {
        alo0 += __shfl_xor(alo0, s, 64); alo1 += __shfl_xor(alo1, s, 64);
        alo2 += __shfl_xor(alo2, s, 64); alo3 += __shfl_xor(alo3, s, 64);
        ahi0 += __shfl_xor(ahi0, s, 64); ahi1 += __shfl_xor(ahi1, s, 64);
        ahi2 += __shfl_xor(ahi2, s, 64); ahi3 += __shfl_xor(ahi3, s, 64);
    }

    // combine + LayerNorm (lane holds channels 4*l15..+3 and +64..; duplicated across quarters)
    size_t bb = (size_t)n * DIM;
    float4 hs0 = *(const float4*)(h_self + bb + 4 * l15);
    float4 hs1 = *(const float4*)(h_self + bb + 64 + 4 * l15);
    float4 b0 = *(const float4*)(bias + 4 * l15);
    float4 b1 = *(const float4*)(bias + 64 + 4 * l15);
    float x0 = hs0.x + alo0 + b0.x;
    float x1 = hs0.y + alo1 + b0.y;
    float x2 = hs0.z + alo2 + b0.z;
    float x3 = hs0.w + alo3 + b0.w;
    float y0 = hs1.x + ahi0 + b1.x;
    float y1 = hs1.y + ahi1 + b1.y;
    float y2 = hs1.z + ahi2 + b1.z;
    float y3 = hs1.w + ahi3 + b1.w;
    float sum = x0 + x1 + x2 + x3 + y0 + y1 + y2 + y3;
    float sq = x0 * x0 + x1 * x1 + x2 * x2 + x3 * x3
             + y0 * y0 + y1 * y1 + y2 * y2 + y3 * y3;
#pragma unroll
    for (int m = 1; m < 64; m <<= 1) {
        sum += __shfl_xor(sum, m, 64);
        sq += __shfl_xor(sq, m, 64);
    }
    float mean = sum * (1.f / 512.f);          // each channel counted 4x
    float var = sq * (1.f / 512.f) - mean * mean;
    float inv = rsqrtf(var + EPS_LN);
    if (lane < 16) {
        float4 g0 = *(const float4*)(gamma + 4 * l15);
        float4 g1 = *(const float4*)(gamma + 64 + 4 * l15);
        float4 be0 = *(const float4*)(beta + 4 * l15);
        float4 be1 = *(const float4*)(beta + 64 + 4 * l15);
        float4 o0 = make_float4((x0 - mean) * inv * g0.x + be0.x,
                                (x1 - mean) * inv * g0.y + be0.y,
                                (x2 - mean) * inv * g0.z + be0.z,
                                (x3 - mean) * inv * g0.w + be0.w);
        float4 o1 = make_float4((y0 - mean) * inv * g1.x + be1.x,
                                (y1 - mean) * inv * g1.y + be1.y,
                                (y2 - mean) * inv * g1.z + be1.z,
                                (y3 - mean) * inv * g1.w + be1.w);
        *(float4*)(out + bb + 4 * l15) = o0;
        *(float4*)(out + bb + 64 + 4 * l15) = o1;
    }
}

extern "C" void kernel_launch(void* const* d_in, const int* in_sizes, int n_in,
                              void* d_out, int out_size, void* d_ws, size_t ws_size,
                              hipStream_t stream) {
    const float* h      = (const float*)d_in[0];
    const int*   ei     = (const int*)d_in[1];
    const float* W      = (const float*)d_in[2];
    const float* W_self = (const float*)d_in[3];
    const float* a_in   = (const float*)d_in[4];
    const float* a_out  = (const float*)d_in[5];
    const float* bias   = (const float*)d_in[6];
    const float* gamma  = (const float*)d_in[7];
    const float* beta   = (const float*)d_in[8];
    float* out = (float*)d_out;

    const int N = in_sizes[0] / DIM;
    const int E = in_sizes[1] / 2;
    const int M = 2 * N;
    const int NBIN = (M + (1 << SH1) - 1) >> SH1;
    const int twoE = 2 * E;

    // workspace layout
    float* ws = (float*)d_ws;
    size_t off_f = 0;
    float* h_self = ws + off_f; off_f += (size_t)N * DIM;
    unsigned* hp_pk = (unsigned*)(ws + off_f); off_f += (size_t)N * 64;
    float* pA0 = ws + off_f; off_f += (size_t)N * 4;
    float* pA1 = ws + off_f; off_f += (size_t)N * 4;
    float* pB0 = ws + off_f; off_f += (size_t)N * 4;
    float* pB1 = ws + off_f; off_f += (size_t)N * 4;
    int* ip = (int*)(ws + off_f);
    size_t off_i = 0;
    int* cntmat = ip + off_i; off_i += (size_t)NBIN * PB;
    int* blkoff = ip + off_i; off_i += (size_t)NBIN * PB;
    int* btot   = ip + off_i; off_i += NBIN;
    int* bbase  = ip + off_i; off_i += (size_t)NBIN + 1;
    int* off    = ip + off_i; off_i += (size_t)M + 1;
    unsigned* rec = (unsigned*)(ip + off_i); off_i += (size_t)twoE;
    int* csr    = ip + off_i; off_i += (size_t)twoE;

    // ---- deterministic two-level CSR build ----
    part1a_k<<<PB, 256, 0, stream>>>(ei, cntmat, E, N, NBIN);
    scanB_k<<<NBIN, PB, 0, stream>>>(cntmat, blkoff, btot);
    scanC_k<<<1, 256, 0, stream>>>(btot, bbase, NBIN, twoE);
    part1b_k<<<PB, 256, 0, stream>>>(ei, bbase, blkoff, rec, E, N, NBIN);
    build2_k<<<NBIN, 256, 0, stream>>>(rec, bbase, off, csr, M, twoE, NBIN);

    // ---- fused projections + dots + pack ----
    dual_gemm_k<<<(N + GROWS - 1) / GROWS, 256, 0, stream>>>(h, W, W_self, a_in, a_out,
                                                             h_self, hp_pk, pA0, pA1, pB0, pB1, N);

    // ---- fused aggregate + LN ----
    node_aggr_ln_k<<<(N + 3) / 4, 256, 0, stream>>>(hp_pk, h_self, pA0, pA1, pB0, pB1,
                                                    off, csr, bias, gamma, beta, out, N);
}